// Round 8
// baseline (815.791 us; speedup 1.0000x reference)
//
#include <hip/hip_runtime.h>
#include <hip/hip_bf16.h>

// ---------------------------------------------------------------------------
// Transformer-XL block on MI355X.  Shapes: B=2, S=1024, M=1024, F=2048,
// D=1024, H=16, dh=64.  Outputs: out[2M] fp32, attn[2*16*1024*2048] fp32,
// loss[1] fp32.
// ---------------------------------------------------------------------------

typedef __attribute__((ext_vector_type(8))) short bf16x8;
typedef __attribute__((ext_vector_type(4))) float f32x4;

#define MFMA16(a, b, c) __builtin_amdgcn_mfma_f32_16x16x32_bf16((a), (b), (c), 0, 0, 0)

__device__ __forceinline__ unsigned short f2bf(float f) {
  union { __hip_bfloat16 h; unsigned short u; } cv;
  cv.h = __float2bfloat16(f);
  return cv.u;
}

__device__ __forceinline__ float bf2f(unsigned short u) {
  return __uint_as_float((unsigned)u << 16);
}

__device__ __forceinline__ float gelu_f(float x) {
  return 0.5f * x * (1.f + erff(x * 0.70710678118654752f));
}

struct W9 { const float* p[9]; };

// ---------------------------------------------------------------------------
// k_init: [0,4096): LN(concat(mem,inputs))->xt bf16, inputs->inb bf16;
// [4096,6144): rel_enc->reb; [6144,8448): weights -> wT bf16 transposed.
// ---------------------------------------------------------------------------
__global__ __launch_bounds__(256) void k_init(
    const float* __restrict__ inputs, const float* __restrict__ mem,
    const float* __restrict__ rel_enc, const float* __restrict__ g1n,
    const float* __restrict__ b1n, W9 wp,
    unsigned short* __restrict__ xt, unsigned short* __restrict__ inb,
    unsigned short* __restrict__ reb, unsigned short* __restrict__ wT,
    float* __restrict__ amax) {
  int bid = blockIdx.x, tid = threadIdx.x;
  if (bid == 0 && tid < 32) amax[tid] = 0.f;
  if (bid < 4096) {
    __shared__ float red[8];
    int b = bid >> 11, fi = bid & 2047;
    const float* src = (fi < 1024)
        ? (mem + ((size_t)(b * 1024 + fi)) * 1024)
        : (inputs + ((size_t)(b * 1024 + fi - 1024)) * 1024);
    float4 x = ((const float4*)src)[tid];
    float s = x.x + x.y + x.z + x.w;
    float ss = x.x * x.x + x.y * x.y + x.z * x.z + x.w * x.w;
#pragma unroll
    for (int m = 32; m > 0; m >>= 1) {
      s += __shfl_down(s, m, 64);
      ss += __shfl_down(ss, m, 64);
    }
    int w = tid >> 6;
    if ((tid & 63) == 0) { red[w] = s; red[4 + w] = ss; }
    __syncthreads();
    s = red[0] + red[1] + red[2] + red[3];
    ss = red[4] + red[5] + red[6] + red[7];
    float mu = s * (1.f / 1024.f);
    float inv = rsqrtf(ss * (1.f / 1024.f) - mu * mu + 1e-5f);
    float4 g = ((const float4*)g1n)[tid];
    float4 bb = ((const float4*)b1n)[tid];
    ushort4 o;
    o.x = f2bf((x.x - mu) * inv * g.x + bb.x);
    o.y = f2bf((x.y - mu) * inv * g.y + bb.y);
    o.z = f2bf((x.z - mu) * inv * g.z + bb.z);
    o.w = f2bf((x.w - mu) * inv * g.w + bb.w);
    ((ushort4*)(xt + (size_t)bid * 1024))[tid] = o;
    if (fi >= 1024) {
      ushort4 r4;
      r4.x = f2bf(x.x); r4.y = f2bf(x.y); r4.z = f2bf(x.z); r4.w = f2bf(x.w);
      ((ushort4*)(inb + ((size_t)(b * 1024 + fi - 1024)) * 1024))[tid] = r4;
    }
  } else if (bid < 6144) {
    int r = bid - 4096;
    float4 x = ((const float4*)(rel_enc + (size_t)r * 1024))[tid];
    ushort4 o;
    o.x = f2bf(x.x); o.y = f2bf(x.y); o.z = f2bf(x.z); o.w = f2bf(x.w);
    ((ushort4*)(reb + (size_t)r * 1024))[tid] = o;
  } else {
    __shared__ float tl[64][65];
    int idx = bid - 6144;
    int m = idx >> 8;
    int t = idx & 255;
    int k0 = (t >> 4) << 6, n0 = (t & 15) << 6;
    const float* srcw = wp.p[m];
    int kr = tid >> 4, nc = (tid & 15) << 2;
#pragma unroll
    for (int i = 0; i < 4; ++i) {
      int krow = i * 16 + kr;
      float4 v = *(const float4*)(srcw + (size_t)(k0 + krow) * 1024 + n0 + nc);
      tl[nc + 0][krow] = v.x;
      tl[nc + 1][krow] = v.y;
      tl[nc + 2][krow] = v.z;
      tl[nc + 3][krow] = v.w;
    }
    __syncthreads();
    int n = tid >> 2, kc0 = (tid & 3) << 4;
    unsigned short* dst = wT + ((size_t)m << 20) + (size_t)(n0 + n) * 1024 + k0 + kc0;
#pragma unroll
    for (int q = 0; q < 4; ++q) {
      ushort4 o;
      o.x = f2bf(tl[n][kc0 + q * 4 + 0]);
      o.y = f2bf(tl[n][kc0 + q * 4 + 1]);
      o.z = f2bf(tl[n][kc0 + q * 4 + 2]);
      o.w = f2bf(tl[n][kc0 + q * 4 + 3]);
      *(ushort4*)(dst + q * 4) = o;
    }
  }
}

// ---------------------------------------------------------------------------
// k_ln: LayerNorm rows of fp32 (2048 x 1024) -> bf16
// ---------------------------------------------------------------------------
__global__ __launch_bounds__(256) void k_ln(
    const float* __restrict__ xin, const float* __restrict__ g1n,
    const float* __restrict__ b1n, unsigned short* __restrict__ outb) {
  __shared__ float red[8];
  int bid = blockIdx.x, tid = threadIdx.x;
  const float* src = xin + (size_t)bid * 1024;
  float4 x = ((const float4*)src)[tid];
  float s = x.x + x.y + x.z + x.w;
  float ss = x.x * x.x + x.y * x.y + x.z * x.z + x.w * x.w;
#pragma unroll
  for (int m = 32; m > 0; m >>= 1) {
    s += __shfl_down(s, m, 64);
    ss += __shfl_down(ss, m, 64);
  }
  int w = tid >> 6;
  if ((tid & 63) == 0) { red[w] = s; red[4 + w] = ss; }
  __syncthreads();
  s = red[0] + red[1] + red[2] + red[3];
  ss = red[4] + red[5] + red[6] + red[7];
  float mu = s * (1.f / 1024.f);
  float inv = rsqrtf(ss * (1.f / 1024.f) - mu * mu + 1e-5f);
  float4 g = ((const float4*)g1n)[tid];
  float4 bb = ((const float4*)b1n)[tid];
  ushort4 o;
  o.x = f2bf((x.x - mu) * inv * g.x + bb.x);
  o.y = f2bf((x.y - mu) * inv * g.y + bb.y);
  o.z = f2bf((x.z - mu) * inv * g.z + bb.z);
  o.w = f2bf((x.w - mu) * inv * g.w + bb.w);
  ((ushort4*)(outb + (size_t)bid * 1024))[tid] = o;
}

// ---------------------------------------------------------------------------
// GEMM: C[M,Nt] = A[M,1024] @ Wt[Nt,1024]^T, tile TM x 128, BK=64, 4 waves
// split the 128-col dim.  Double-buffered LDS (1 barrier/iter).
// Occupancy: TM=32 -> LDS 40 KB -> 4 blocks/CU; TM=64 -> 48 KB -> 3.
// ---------------------------------------------------------------------------
__device__ __forceinline__ int lds_u128(int r, int g) {
  return g * 128 + (r & ~7) + ((r ^ g) & 7);
}
template <int TM>
__device__ __forceinline__ int lds_uT(int r, int g) {
  return g * TM + (r & ~7) + ((r ^ g) & 7);
}

enum { EP_KV = 0, EP_QUV, EP_BF16, EP_GELU_F32, EP_GATE1,
       EP_GELU_B_BF16, EP_GELU_B_F32, EP_GATE2 };

template <int EP, int TM>
__global__ __launch_bounds__(256, TM == 32 ? 4 : 3) void k_gemm(
    const unsigned short* __restrict__ A, const unsigned short* __restrict__ Bw,
    int arow_add, int arow_mul,
    const float* __restrict__ bias, const float* __restrict__ auxA,
    const float* __restrict__ auxB, void* __restrict__ out0,
    void* __restrict__ out1) {
  constexpr int MI = TM / 16;
  constexpr int AU = TM / 32;
  __shared__ __align__(16) unsigned short As[2][TM * 64];
  __shared__ __align__(16) unsigned short Bs[2][128 * 64];
  int tid = threadIdx.x;
  int lane = tid & 63, wave = tid >> 6;
  int quad = lane >> 4, col = lane & 15;
  int bm = blockIdx.y, bn = blockIdx.x;
  f32x4 acc[MI][2] = {};
  int str = tid >> 3, stg = tid & 7;
  const unsigned short* aptr[AU];
  int au[AU];
  const unsigned short* bptr[4];
  int bu[4];
#pragma unroll
  for (int i = 0; i < AU; ++i) {
    int r = str + 32 * i;
    int gr = bm * TM + r;
    int ar = gr + arow_add + (gr >> 10) * arow_mul;
    aptr[i] = A + (size_t)ar * 1024 + stg * 8;
    au[i] = lds_uT<TM>(r, stg);
  }
#pragma unroll
  for (int i = 0; i < 4; ++i) {
    int r = str + 32 * i;
    bptr[i] = Bw + (size_t)(bn * 128 + r) * 1024 + stg * 8;
    bu[i] = lds_u128(r, stg);
  }
  uint4 av[AU], bv[4];
#pragma unroll
  for (int i = 0; i < AU; ++i) av[i] = *(const uint4*)(aptr[i]);
#pragma unroll
  for (int i = 0; i < 4; ++i) bv[i] = *(const uint4*)(bptr[i]);
#pragma unroll
  for (int i = 0; i < AU; ++i) ((uint4*)As[0])[au[i]] = av[i];
#pragma unroll
  for (int i = 0; i < 4; ++i) ((uint4*)Bs[0])[bu[i]] = bv[i];
  for (int kt = 0; kt < 16; ++kt) {
    __syncthreads();
    if (kt < 15) {
      int k0 = (kt + 1) * 64;
#pragma unroll
      for (int i = 0; i < AU; ++i) av[i] = *(const uint4*)(aptr[i] + k0);
#pragma unroll
      for (int i = 0; i < 4; ++i) bv[i] = *(const uint4*)(bptr[i] + k0);
    }
    int cur = kt & 1;
#pragma unroll
    for (int ks = 0; ks < 2; ++ks) {
      bf16x8 af[MI], bfr[2];
#pragma unroll
      for (int mi = 0; mi < MI; ++mi)
        af[mi] = ((const bf16x8*)As[cur])[lds_uT<TM>(mi * 16 + col, ks * 4 + quad)];
#pragma unroll
      for (int ni = 0; ni < 2; ++ni)
        bfr[ni] = ((const bf16x8*)Bs[cur])[lds_u128(wave * 32 + ni * 16 + col, ks * 4 + quad)];
#pragma unroll
      for (int mi = 0; mi < MI; ++mi)
#pragma unroll
        for (int ni = 0; ni < 2; ++ni)
          acc[mi][ni] = MFMA16(af[mi], bfr[ni], acc[mi][ni]);
    }
    if (kt < 15) {
      int nxt = cur ^ 1;
#pragma unroll
      for (int i = 0; i < AU; ++i) ((uint4*)As[nxt])[au[i]] = av[i];
#pragma unroll
      for (int i = 0; i < 4; ++i) ((uint4*)Bs[nxt])[bu[i]] = bv[i];
    }
  }
#pragma unroll
  for (int mi = 0; mi < MI; ++mi)
#pragma unroll
    for (int ni = 0; ni < 2; ++ni)
#pragma unroll
      for (int r = 0; r < 4; ++r) {
        int grow = bm * TM + mi * 16 + quad * 4 + r;
        int gcol = bn * 128 + wave * 32 + ni * 16 + col;
        float v = acc[mi][ni][r];
        size_t idx = (size_t)grow * 1024 + gcol;
        if constexpr (EP == EP_KV) {
          if (gcol < 1024) {
            ((unsigned short*)out0)[(size_t)grow * 1024 + gcol] = f2bf(v);
          } else {
            ((unsigned short*)out1)[(size_t)grow * 1024 + gcol - 1024] = f2bf(v);
          }
        } else if constexpr (EP == EP_QUV) {
          ((unsigned short*)out0)[idx] = f2bf(v + auxA[gcol]);
          ((unsigned short*)out1)[idx] = f2bf(v + auxB[gcol]);
        } else if constexpr (EP == EP_BF16) {
          ((unsigned short*)out0)[idx] = f2bf(v);
        } else if constexpr (EP == EP_GELU_F32) {
          ((float*)out0)[idx] = gelu_f(v);
        } else if constexpr (EP == EP_GATE1) {
          float a = v + bias[gcol];
          float sg = 1.f / (1.f + __expf(-a));
          float g1 = auxA[idx] + sg * auxB[idx];
          ((float*)out0)[idx] = g1;
          ((unsigned short*)out1)[idx] = f2bf(g1);
        } else if constexpr (EP == EP_GELU_B_BF16) {
          ((unsigned short*)out0)[idx] = f2bf(gelu_f(v + bias[gcol]));
        } else if constexpr (EP == EP_GELU_B_F32) {
          ((float*)out0)[idx] = gelu_f(v + bias[gcol]);
        } else {  // EP_GATE2
          float a = v + bias[gcol];
          float sg = 1.f / (1.f + __expf(-a));
          ((float*)out0)[idx] = auxA[idx] + sg * auxB[idx];
        }
      }
}

// ---------------------------------------------------------------------------
// k_tr: v (b,f,h,d) bf16 -> vT (b,h,d,f) bf16.  grid (32 bh, 32 ftile).
// ---------------------------------------------------------------------------
__global__ __launch_bounds__(256) void k_tr(
    const unsigned short* __restrict__ v, unsigned short* __restrict__ vT) {
  __shared__ unsigned short tl[64][72];
  int bh = blockIdx.x, ft = blockIdx.y;
  int b = bh >> 4, h = bh & 15;
  int f0 = ft * 64;
  int tid = threadIdx.x;
  int fr = tid >> 2, c0 = (tid & 3) * 16;
  *(uint4*)&tl[fr][c0] =
      *(const uint4*)(v + ((size_t)(b * 2048 + f0 + fr)) * 1024 + h * 64 + c0);
  __syncthreads();
  int dr = tid >> 2, fc = (tid & 3) * 16;
  unsigned short* dst =
      vT + (((size_t)(b * 16 + h) * 64 + dr)) * 2048 + f0 + fc;
#pragma unroll
  for (int q = 0; q < 4; ++q) {
    ushort4 o;
    o.x = tl[fc + q * 4 + 0][dr];
    o.y = tl[fc + q * 4 + 1][dr];
    o.z = tl[fc + q * 4 + 2][dr];
    o.w = tl[fc + q * 4 + 3][dr];
    *(ushort4*)(dst + q * 4) = o;
  }
}

// ---------------------------------------------------------------------------
// Fused rel-pos attention, single pass + in-LDS normalize.
// grid (32 = B*H, 64 = S/16); block 1024 = 16 waves; block owns 16 query
// rows.  ONE block owns the whole CU (LDS ~100 KB) -> 16 waves/CU =
// 4 waves/SIMD guaranteed TLP.  (R7 lesson: 512-thr/74.6KB packed only ONE
// block/CU -> 8 waves/CU, same as R2; occupancy never rose.  This design
// doesn't depend on 2-block packing.)
// Wave w takes 32-col chunks {w, w+16, ...} of the ACTIVE range (NA
// chunks); myN = 2..4 per wave.  Plain per-chunk load->compute; latency
// hidden by TLP.  __launch_bounds__(1024,1) -> VGPR cap 128 (R6
// calibration: cap = 131072/(min_blocks*threads)), body needs ~68.
// Pass 1: p (bf16) into Pb[16][2056], rowsum + P@V in regs.
// 16-wave halving ladder (16->8->4->2->1) over Ol[8][1024], WAR-free by
// disjoint slots, 5 barriers.  ao (bf16) + amax.
// Pass 2: stream Pb * rinv -> attn (fp32), regular coalesced f32x4.
// ---------------------------------------------------------------------------
__global__ __launch_bounds__(1024, 1) void k_att(
    const unsigned short* __restrict__ qu, const unsigned short* __restrict__ qv,
    const unsigned short* __restrict__ kk, const unsigned short* __restrict__ vT,
    const unsigned short* __restrict__ Qr,
    float* __restrict__ attn, unsigned short* __restrict__ ao,
    float* __restrict__ amax) {
  __shared__ __align__(16) unsigned short Pb[16][2056];
  __shared__ __align__(16) float Ol[8][1024];
  __shared__ float Sl[16][16];
  __shared__ float Rinv[16];
  int tid = threadIdx.x, lane = tid & 63, wave = tid >> 6;
  int quad = lane >> 4, col = lane & 15;
  int bh = blockIdx.x, rt = blockIdx.y;
  int b = bh >> 4, h = bh & 15;
  int ri = rt * 16;

  bf16x8 quf[2], qvf[2];
  {
    const unsigned short* p0 = qu + ((size_t)(b * 1024 + ri + col)) * 1024 + h * 64 + quad * 8;
    quf[0] = *(const bf16x8*)p0;
    quf[1] = *(const bf16x8*)(p0 + 32);
    const unsigned short* p1 = qv + ((size_t)(b * 1024 + ri + col)) * 1024 + h * 64 + quad * 8;
    qvf[0] = *(const bf16x8*)p1;
    qvf[1] = *(const bf16x8*)(p1 + 32);
  }

  const unsigned short* qrbase = Qr + h * 64 + quad * 8;
  auto r_load = [&](int cbase, bf16x8& b0, bf16x8& b1) {
    int cr = cbase + col;
    cr = cr < 0 ? 0 : (cr > 2047 ? 2047 : cr);
    const unsigned short* p = qrbase + (size_t)cr * 1024;
    b0 = *(const bf16x8*)p;
    b1 = *(const bf16x8*)(p + 32);
  };
  auto r_mm = [&](bf16x8 b0, bf16x8 b1) -> f32x4 {
    f32x4 z = {0.f, 0.f, 0.f, 0.f};
    z = MFMA16(qvf[0], b0, z);
    z = MFMA16(qvf[1], b1, z);
    return z;
  };

  const unsigned short* kbase = kk + ((size_t)(b * 2048)) * 1024 + h * 64 + quad * 8;
  const unsigned short* vbase = vT + ((size_t)((b * 16 + h) * 64)) * 2048;

  f32x4 o4[4] = {};
  f32x4 srow = {0.f, 0.f, 0.f, 0.f};
  f32x4 pm = {0.f, 0.f, 0.f, 0.f};
  int jmax = ri + 15 + 1024;
  int NA = (jmax >> 5) + 1;                 // active 32-col chunks (33..64)
  int myN = (NA - wave + 15) >> 4;          // chunks owned by this wave (2..4)

  {
    int j0 = wave << 5;
    int cw = 1008 - ri + j0;
    for (int i = 0; i < myN; ++i) {
      // ---- loads for this chunk (14 in flight) ----
      bf16x8 rr0, rr1, rr2, rr3, rr4, rr5;
      r_load(cw, rr0, rr1);
      r_load(cw + 16, rr2, rr3);
      r_load(cw + 32, rr4, rr5);
      const unsigned short* kp0 = kbase + (size_t)(j0 + col) * 1024;
      const unsigned short* kp1 = kbase + (size_t)(j0 + 16 + col) * 1024;
      bf16x8 k00 = *(const bf16x8*)kp0;
      bf16x8 k01 = *(const bf16x8*)(kp0 + 32);
      bf16x8 k10 = *(const bf16x8*)kp1;
      bf16x8 k11 = *(const bf16x8*)(kp1 + 32);
      int fb = j0 + quad * 8;
      bf16x8 vf[4];
#pragma unroll
      for (int ni = 0; ni < 4; ++ni)
        vf[ni] = *(const bf16x8*)(vbase + (size_t)(ni * 16 + col) * 2048 + fb);
      // ---- compute ----
      f32x4 R0 = r_mm(rr0, rr1);
      f32x4 R1 = r_mm(rr2, rr3);
      f32x4 R2 = r_mm(rr4, rr5);
      f32x4 ac0 = {0.f, 0.f, 0.f, 0.f};
      ac0 = MFMA16(quf[0], k00, ac0);
      ac0 = MFMA16(quf[1], k01, ac0);
      f32x4 ac1 = {0.f, 0.f, 0.f, 0.f};
      ac1 = MFMA16(quf[0], k10, ac1);
      ac1 = MFMA16(quf[1], k11, ac1);
#pragma unroll
      for (int r = 0; r < 4; ++r) {
        int w = 15 + col - quad * 4 - r;
        int src = quad * 16 + (w & 15);
        float bd0 = __shfl(R0[r], src, 64);
        float bd1 = __shfl(R1[r], src, 64);
        float bd = (w < 16) ? bd0 : bd1;
        float sc = (ac0[r] + bd) * 0.03125f;
        int masked = (j0 + col) > (ri + quad * 4 + r + 1024);
        float p = masked ? 0.f : __expf(sc);
        srow[r] += p;
        pm[r] = fmaxf(pm[r], p);
        Pb[quad * 4 + r][j0 + col] = f2bf(p);
      }
#pragma unroll
      for (int r = 0; r < 4; ++r) {
        int w = 15 + col - quad * 4 - r;
        int src = quad * 16 + (w & 15);
        float bd0 = __shfl(R1[r], src, 64);
        float bd1 = __shfl(R2[r], src, 64);
        float bd = (w < 16) ? bd0 : bd1;
        float sc = (ac1[r] + bd) * 0.03125f;
        int masked = (j0 + 16 + col) > (ri + quad * 4 + r + 1024);
        float p = masked ? 0.f : __expf(sc);
        srow[r] += p;
        pm[r] = fmaxf(pm[r], p);
        Pb[quad * 4 + r][j0 + 16 + col] = f2bf(p);
      }
      asm volatile("s_waitcnt lgkmcnt(0)" ::: "memory");
      bf16x8 pf = *(const bf16x8*)&Pb[col][j0 + quad * 8];
#pragma unroll
      for (int ni = 0; ni < 4; ++ni) o4[ni] = MFMA16(pf, vf[ni], o4[ni]);
      j0 += 512; cw += 512;
    }
  }

  // stripe row-sums / row-max (reduce across the 16 col lanes of each quad)
#pragma unroll
  for (int r = 0; r < 4; ++r) {
    float v = srow[r], m = pm[r];
    v += __shfl_xor(v, 1, 64);  m = fmaxf(m, __shfl_xor(m, 1, 64));
    v += __shfl_xor(v, 2, 64);  m = fmaxf(m, __shfl_xor(m, 2, 64));
    v += __shfl_xor(v, 4, 64);  m = fmaxf(m, __shfl_xor(m, 4, 64));
    v += __shfl_xor(v, 8, 64);  m = fmaxf(m, __shfl_xor(m, 8, 64));
    srow[r] = v; pm[r] = m;
  }
  if (col == 0) {
#pragma unroll
    for (int r = 0; r < 4; ++r) Sl[wave][quad * 4 + r] = srow[r];
  }
  // ---- 16-wave halving ladder over Ol[8][1024] (WAR-free: disjoint slots) --
  if (wave >= 8) {
#pragma unroll
    for (int ni = 0; ni < 4; ++ni)
#pragma unroll
      for (int r = 0; r < 4; ++r)
        Ol[wave - 8][(quad * 4 + r) * 64 + ni * 16 + col] = o4[ni][r];
  }
  __syncthreads();
  if (tid < 16) {
    float s = 0.f;
#pragma unroll
    for (int wv = 0; wv < 16; ++wv) s += Sl[wv][tid];
    Rinv[tid] = 1.f / s;
  }
  if (wave < 8) {
#pragma unroll
    for (int ni = 0; ni < 4; ++ni)
#pragma unroll
      for (int r = 0; r < 4; ++r) {
        int ix = (quad * 4 + r) * 64 + ni * 16 + col;
        o4[ni][r] += Ol[wave][ix];
        if (wave >= 4) Ol[wave][ix] = o4[ni][r];   // waves 4..7 park in Ol[4..7]
      }
  }
  __syncthreads();
  if (wave < 4) {
#pragma unroll
    for (int ni = 0; ni < 4; ++ni)
#pragma unroll
      for (int r = 0; r < 4; ++r) {
        int ix = (quad * 4 + r) * 64 + ni * 16 + col;
        o4[ni][r] += Ol[wave + 4][ix];             // read Ol[4..7]
        if (wave >= 2) Ol[wave][ix] = o4[ni][r];   // waves 2..3 park in Ol[2..3]
      }
  }
  __syncthreads();
  if (wave < 2) {
#pragma unroll
    for (int ni = 0; ni < 4; ++ni)
#pragma unroll
      for (int r = 0; r < 4; ++r) {
        int ix = (quad * 4 + r) * 64 + ni * 16 + col;
        o4[ni][r] += Ol[wave + 2][ix];             // read Ol[2..3]
        if (wave == 1) Ol[1][ix] = o4[ni][r];
      }
  }
  __syncthreads();
  if (wave == 0) {
#pragma unroll
    for (int ni = 0; ni < 4; ++ni)
#pragma unroll
      for (int r = 0; r < 4; ++r) {
        int ix = (quad * 4 + r) * 64 + ni * 16 + col;
        o4[ni][r] += Ol[1][ix];
        Ol[0][ix] = o4[ni][r];
      }
  }
  __syncthreads();
  if (tid < 256) {
    int row = tid >> 4, d0 = (tid & 15) << 2;
    float4 ov = *(const float4*)&Ol[0][row * 64 + d0];
    float rv = Rinv[row];
    ushort4 o;
    o.x = f2bf(ov.x * rv); o.y = f2bf(ov.y * rv);
    o.z = f2bf(ov.z * rv); o.w = f2bf(ov.w * rv);
    *(ushort4*)(ao + ((size_t)(b * 1024 + ri + row)) * 1024 + h * 64 + d0) = o;
  }
  // per-(b,h) max of normalized p
  float pmax = 0.f;
#pragma unroll
  for (int r = 0; r < 4; ++r) pmax = fmaxf(pmax, pm[r] * Rinv[quad * 4 + r]);
  pmax = fmaxf(pmax, __shfl_xor(pmax, 16, 64));
  pmax = fmaxf(pmax, __shfl_xor(pmax, 32, 64));
  if (lane == 0) atomicMax((int*)(amax + bh), __float_as_int(pmax));

  // ---- pass 2: normalized attn write (regular coalesced f32x4, mask -> 0) --
  {
    float* abase = attn + ((size_t)bh * 1024 + ri) * 2048;
#pragma unroll 4
    for (int it = 0; it < 8; ++it) {
      int idx = it * 1024 + tid;     // 8192 f32x4 units = 16 rows x 512
      int row = idx >> 9;
      int j = (idx & 511) << 2;
      float rv = Rinv[row];
      int lim = ri + row + 1024;
      ushort4 p4 = *(const ushort4*)&Pb[row][j];
      f32x4 o;
      o[0] = (j + 0 <= lim) ? bf2f(p4.x) * rv : 0.f;
      o[1] = (j + 1 <= lim) ? bf2f(p4.y) * rv : 0.f;
      o[2] = (j + 2 <= lim) ? bf2f(p4.z) * rv : 0.f;
      o[3] = (j + 3 <= lim) ? bf2f(p4.w) * rv : 0.f;
      *(f32x4*)(abase + (size_t)row * 2048 + j) = o;
    }
  }
}

// ---------------------------------------------------------------------------
__global__ void k_loss(const float* __restrict__ amax, float* __restrict__ out) {
  int l = threadIdx.x;
  float v = (l < 32) ? amax[l] : 0.f;
  v += __shfl_xor(v, 1, 64);
  v += __shfl_xor(v, 2, 64);
  v += __shfl_xor(v, 4, 64);
  v += __shfl_xor(v, 8, 64);
  v += __shfl_xor(v, 16, 64);
  v += __shfl_xor(v, 32, 64);
  if (l == 0) out[0] = v * (1.f / 32.f);
}

// ---------------------------------------------------------------------------
extern "C" void kernel_launch(void* const* d_in, const int* in_sizes, int n_in,
                              void* d_out, int out_size, void* d_ws, size_t ws_size,
                              hipStream_t stream) {
  (void)in_sizes; (void)n_in; (void)out_size; (void)ws_size;
  const float* inputs = (const float*)d_in[0];
  const float* mem    = (const float*)d_in[1];
  const float* rel    = (const float*)d_in[2];
  const float* ln1g   = (const float*)d_in[4];
  const float* ln1b   = (const float*)d_in[5];
  const float* wq     = (const float*)d_in[6];
  const float* wke    = (const float*)d_in[7];
  const float* wkr    = (const float*)d_in[8];
  const float* wv     = (const float*)d_in[9];
  const float* wf     = (const float*)d_in[10];
  const float* up     = (const float*)d_in[11];
  const float* vp     = (const float*)d_in[12];
  const float* ln2g   = (const float*)d_in[13];
  const float* ln2b   = (const float*)d_in[14];
  const float* w1     = (const float*)d_in[15];
  const float* b1     = (const float*)d_in[16];
  const float* w2     = (const float*)d_in[17];
  const float* b2     = (const float*)d_in[18];
  const float* wg1    = (const float*)d_in[19];
  const float* bg1    = (const float*)d_in[20];
  const float* wg2    = (const float*)d_in[21];
  const float* bg2    = (const float*)d_in[22];

  char* ws = (char*)d_ws;
  unsigned short* wT  = (unsigned short*)(ws);              // 18 MB (9 x 1Mel)
  unsigned short* xt  = (unsigned short*)(ws + 18874368);   // 8 MB
  unsigned short* inb = (unsigned short*)(ws + 27262976);   // 4 MB
  unsigned short* reb = (unsigned short*)(ws + 31457280);   // 4 MB
  unsigned short* kb  = (unsigned short*)(ws + 35651584);   // 8 MB
  unsigned short* vTb = (unsigned short*)(ws + 44040192);   // 8 MB
  unsigned short* qub = (unsigned short*)(ws + 52428800);   // 4 MB
  unsigned short* qvb = (unsigned short*)(ws + 56623104);   // 4 MB
  unsigned short* Qrb = (unsigned short*)(ws + 60817408);   // 4 MB
  float* amax         = (float*)(ws + 65011712);            // 128 B
  // aliases onto dead buffers:
  unsigned short* vb = qub;          // v row-major, dead after k_tr (8 MB)
  float* rmha = (float*)xt;
  unsigned short* aob = reb;
  float* g1f = (float*)kb;
  float* h2f = (float*)vTb;
  unsigned short* g1b = qub;
  unsigned short* h0b = qvb;
  unsigned short* h1b = Qrb;

  float* outp  = (float*)d_out;
  float* attnp = outp + 2097152;
  float* lossp = outp + 69206016;

  W9 wp;
  wp.p[0] = wq;  wp.p[1] = wke; wp.p[2] = wv;  wp.p[3] = wkr; wp.p[4] = wf;
  wp.p[5] = w1;  wp.p[6] = w2;  wp.p[7] = wg1; wp.p[8] = wg2;

  k_init<<<8448, 256, 0, stream>>>(inputs, mem, rel, ln1g, ln1b, wp,
                                   xt, inb, reb, wT, amax);
  // k|v fused: (B*F,1024) @ [wke|wv]^T  (N=2048); both halves row-major
  k_gemm<EP_KV, 64><<<dim3(16, 64), 256, 0, stream>>>(
      xt, wT + (1u << 20), 0, 0, nullptr, nullptr, nullptr, kb, vb);
  // vT (b,h,d,f) from v (b,f,h,d)
  k_tr<<<dim3(32, 32), 256, 0, stream>>>(vb, vTb);
  // q -> qu = q+u_param, qv = q+v_param  (A rows = x_tilde[:, -S:]) — clobbers vb
  k_gemm<EP_QUV, 32><<<dim3(8, 64), 256, 0, stream>>>(
      xt, wT, 1024, 1024, nullptr, up, vp, qub, qvb);
  // Qr = rel_enc @ wkr
  k_gemm<EP_BF16, 32><<<dim3(8, 64), 256, 0, stream>>>(
      reb, wT + 3u * (1u << 20), 0, 0, nullptr, nullptr, nullptr, Qrb, nullptr);
  // attention: normalized attn directly (in-LDS p tile), ao, amax
  k_att<<<dim3(32, 64), 1024, 0, stream>>>(qub, qvb, kb, vTb, Qrb,
                                           attnp, aob, amax);
  // rmha = gelu(ao @ wf)
  k_gemm<EP_GELU_F32, 32><<<dim3(8, 64), 256, 0, stream>>>(
      aob, wT + 4u * (1u << 20), 0, 0, nullptr, nullptr, nullptr, rmha, nullptr);
  // g1 = inputs + sigmoid(inputs@wg1 + bg1) * rmha
  k_gemm<EP_GATE1, 32><<<dim3(8, 64), 256, 0, stream>>>(
      inb, wT + 7u * (1u << 20), 0, 0, bg1, inputs, rmha, g1f, g1b);
  // h0 = LN2(g1)
  k_ln<<<2048, 256, 0, stream>>>(g1f, ln2g, ln2b, h0b);
  // h1 = gelu(h0@w1 + b1)
  k_gemm<EP_GELU_B_BF16, 32><<<dim3(8, 64), 256, 0, stream>>>(
      h0b, wT + 5u * (1u << 20), 0, 0, b1, nullptr, nullptr, h1b, nullptr);
  // h2 = gelu(h1@w2 + b2)
  k_gemm<EP_GELU_B_F32, 32><<<dim3(8, 64), 256, 0, stream>>>(
      h1b, wT + 6u * (1u << 20), 0, 0, b2, nullptr, nullptr, h2f, nullptr);
  // out = g1 + sigmoid(g1@wg2 + bg2) * h2
  k_gemm<EP_GATE2, 32><<<dim3(8, 64), 256, 0, stream>>>(
      g1b, wT + 8u * (1u << 20), 0, 0, bg2, g1f, h2f, outp, nullptr);
  k_loss<<<1, 64, 0, stream>>>(amax, lossp);
}

// Round 9
// 710.868 us; speedup vs baseline: 1.1476x; 1.1476x over previous
//
#include <hip/hip_runtime.h>
#include <hip/hip_bf16.h>

// ---------------------------------------------------------------------------
// Transformer-XL block on MI355X.  Shapes: B=2, S=1024, M=1024, F=2048,
// D=1024, H=16, dh=64.  Outputs: out[2M] fp32, attn[2*16*1024*2048] fp32,
// loss[1] fp32.
// ---------------------------------------------------------------------------

typedef __attribute__((ext_vector_type(8))) short bf16x8;
typedef __attribute__((ext_vector_type(4))) float f32x4;

#define MFMA16(a, b, c) __builtin_amdgcn_mfma_f32_16x16x32_bf16((a), (b), (c), 0, 0, 0)

__device__ __forceinline__ unsigned short f2bf(float f) {
  union { __hip_bfloat16 h; unsigned short u; } cv;
  cv.h = __float2bfloat16(f);
  return cv.u;
}

__device__ __forceinline__ float bf2f(unsigned short u) {
  return __uint_as_float((unsigned)u << 16);
}

__device__ __forceinline__ float gelu_f(float x) {
  return 0.5f * x * (1.f + erff(x * 0.70710678118654752f));
}

struct W9 { const float* p[9]; };

// ---------------------------------------------------------------------------
// k_init: [0,4096): LN(concat(mem,inputs))->xt bf16, inputs->inb bf16;
// [4096,6144): rel_enc->reb; [6144,8448): weights -> wT bf16 transposed.
// ---------------------------------------------------------------------------
__global__ __launch_bounds__(256) void k_init(
    const float* __restrict__ inputs, const float* __restrict__ mem,
    const float* __restrict__ rel_enc, const float* __restrict__ g1n,
    const float* __restrict__ b1n, W9 wp,
    unsigned short* __restrict__ xt, unsigned short* __restrict__ inb,
    unsigned short* __restrict__ reb, unsigned short* __restrict__ wT,
    float* __restrict__ amax) {
  int bid = blockIdx.x, tid = threadIdx.x;
  if (bid == 0 && tid < 32) amax[tid] = 0.f;
  if (bid < 4096) {
    __shared__ float red[8];
    int b = bid >> 11, fi = bid & 2047;
    const float* src = (fi < 1024)
        ? (mem + ((size_t)(b * 1024 + fi)) * 1024)
        : (inputs + ((size_t)(b * 1024 + fi - 1024)) * 1024);
    float4 x = ((const float4*)src)[tid];
    float s = x.x + x.y + x.z + x.w;
    float ss = x.x * x.x + x.y * x.y + x.z * x.z + x.w * x.w;
#pragma unroll
    for (int m = 32; m > 0; m >>= 1) {
      s += __shfl_down(s, m, 64);
      ss += __shfl_down(ss, m, 64);
    }
    int w = tid >> 6;
    if ((tid & 63) == 0) { red[w] = s; red[4 + w] = ss; }
    __syncthreads();
    s = red[0] + red[1] + red[2] + red[3];
    ss = red[4] + red[5] + red[6] + red[7];
    float mu = s * (1.f / 1024.f);
    float inv = rsqrtf(ss * (1.f / 1024.f) - mu * mu + 1e-5f);
    float4 g = ((const float4*)g1n)[tid];
    float4 bb = ((const float4*)b1n)[tid];
    ushort4 o;
    o.x = f2bf((x.x - mu) * inv * g.x + bb.x);
    o.y = f2bf((x.y - mu) * inv * g.y + bb.y);
    o.z = f2bf((x.z - mu) * inv * g.z + bb.z);
    o.w = f2bf((x.w - mu) * inv * g.w + bb.w);
    ((ushort4*)(xt + (size_t)bid * 1024))[tid] = o;
    if (fi >= 1024) {
      ushort4 r4;
      r4.x = f2bf(x.x); r4.y = f2bf(x.y); r4.z = f2bf(x.z); r4.w = f2bf(x.w);
      ((ushort4*)(inb + ((size_t)(b * 1024 + fi - 1024)) * 1024))[tid] = r4;
    }
  } else if (bid < 6144) {
    int r = bid - 4096;
    float4 x = ((const float4*)(rel_enc + (size_t)r * 1024))[tid];
    ushort4 o;
    o.x = f2bf(x.x); o.y = f2bf(x.y); o.z = f2bf(x.z); o.w = f2bf(x.w);
    ((ushort4*)(reb + (size_t)r * 1024))[tid] = o;
  } else {
    __shared__ float tl[64][65];
    int idx = bid - 6144;
    int m = idx >> 8;
    int t = idx & 255;
    int k0 = (t >> 4) << 6, n0 = (t & 15) << 6;
    const float* srcw = wp.p[m];
    int kr = tid >> 4, nc = (tid & 15) << 2;
#pragma unroll
    for (int i = 0; i < 4; ++i) {
      int krow = i * 16 + kr;
      float4 v = *(const float4*)(srcw + (size_t)(k0 + krow) * 1024 + n0 + nc);
      tl[nc + 0][krow] = v.x;
      tl[nc + 1][krow] = v.y;
      tl[nc + 2][krow] = v.z;
      tl[nc + 3][krow] = v.w;
    }
    __syncthreads();
    int n = tid >> 2, kc0 = (tid & 3) << 4;
    unsigned short* dst = wT + ((size_t)m << 20) + (size_t)(n0 + n) * 1024 + k0 + kc0;
#pragma unroll
    for (int q = 0; q < 4; ++q) {
      ushort4 o;
      o.x = f2bf(tl[n][kc0 + q * 4 + 0]);
      o.y = f2bf(tl[n][kc0 + q * 4 + 1]);
      o.z = f2bf(tl[n][kc0 + q * 4 + 2]);
      o.w = f2bf(tl[n][kc0 + q * 4 + 3]);
      *(ushort4*)(dst + q * 4) = o;
    }
  }
}

// ---------------------------------------------------------------------------
// k_ln: LayerNorm rows of fp32 (2048 x 1024) -> bf16
// ---------------------------------------------------------------------------
__global__ __launch_bounds__(256) void k_ln(
    const float* __restrict__ xin, const float* __restrict__ g1n,
    const float* __restrict__ b1n, unsigned short* __restrict__ outb) {
  __shared__ float red[8];
  int bid = blockIdx.x, tid = threadIdx.x;
  const float* src = xin + (size_t)bid * 1024;
  float4 x = ((const float4*)src)[tid];
  float s = x.x + x.y + x.z + x.w;
  float ss = x.x * x.x + x.y * x.y + x.z * x.z + x.w * x.w;
#pragma unroll
  for (int m = 32; m > 0; m >>= 1) {
    s += __shfl_down(s, m, 64);
    ss += __shfl_down(ss, m, 64);
  }
  int w = tid >> 6;
  if ((tid & 63) == 0) { red[w] = s; red[4 + w] = ss; }
  __syncthreads();
  s = red[0] + red[1] + red[2] + red[3];
  ss = red[4] + red[5] + red[6] + red[7];
  float mu = s * (1.f / 1024.f);
  float inv = rsqrtf(ss * (1.f / 1024.f) - mu * mu + 1e-5f);
  float4 g = ((const float4*)g1n)[tid];
  float4 bb = ((const float4*)b1n)[tid];
  ushort4 o;
  o.x = f2bf((x.x - mu) * inv * g.x + bb.x);
  o.y = f2bf((x.y - mu) * inv * g.y + bb.y);
  o.z = f2bf((x.z - mu) * inv * g.z + bb.z);
  o.w = f2bf((x.w - mu) * inv * g.w + bb.w);
  ((ushort4*)(outb + (size_t)bid * 1024))[tid] = o;
}

// ---------------------------------------------------------------------------
// GEMM: C[M,Nt] = A[M,1024] @ Wt[Nt,1024]^T, tile TM x 128, BK=64, 4 waves
// split the 128-col dim.  Double-buffered LDS (1 barrier/iter).
// EP_KV writes k in (b,h,f,d) layout and EP_QR writes Qr in (h,f,d) layout
// so k_att's per-chunk K/rel loads are CONTIGUOUS (see k_att header).
// ---------------------------------------------------------------------------
__device__ __forceinline__ int lds_u128(int r, int g) {
  return g * 128 + (r & ~7) + ((r ^ g) & 7);
}
template <int TM>
__device__ __forceinline__ int lds_uT(int r, int g) {
  return g * TM + (r & ~7) + ((r ^ g) & 7);
}

enum { EP_KV = 0, EP_QUV, EP_QR, EP_GELU_F32, EP_GATE1,
       EP_GELU_B_BF16, EP_GELU_B_F32, EP_GATE2 };

template <int EP, int TM>
__global__ __launch_bounds__(256, TM == 32 ? 4 : 3) void k_gemm(
    const unsigned short* __restrict__ A, const unsigned short* __restrict__ Bw,
    int arow_add, int arow_mul,
    const float* __restrict__ bias, const float* __restrict__ auxA,
    const float* __restrict__ auxB, void* __restrict__ out0,
    void* __restrict__ out1) {
  constexpr int MI = TM / 16;
  constexpr int AU = TM / 32;
  __shared__ __align__(16) unsigned short As[2][TM * 64];
  __shared__ __align__(16) unsigned short Bs[2][128 * 64];
  int tid = threadIdx.x;
  int lane = tid & 63, wave = tid >> 6;
  int quad = lane >> 4, col = lane & 15;
  int bm = blockIdx.y, bn = blockIdx.x;
  f32x4 acc[MI][2] = {};
  int str = tid >> 3, stg = tid & 7;
  const unsigned short* aptr[AU];
  int au[AU];
  const unsigned short* bptr[4];
  int bu[4];
#pragma unroll
  for (int i = 0; i < AU; ++i) {
    int r = str + 32 * i;
    int gr = bm * TM + r;
    int ar = gr + arow_add + (gr >> 10) * arow_mul;
    aptr[i] = A + (size_t)ar * 1024 + stg * 8;
    au[i] = lds_uT<TM>(r, stg);
  }
#pragma unroll
  for (int i = 0; i < 4; ++i) {
    int r = str + 32 * i;
    bptr[i] = Bw + (size_t)(bn * 128 + r) * 1024 + stg * 8;
    bu[i] = lds_u128(r, stg);
  }
  uint4 av[AU], bv[4];
#pragma unroll
  for (int i = 0; i < AU; ++i) av[i] = *(const uint4*)(aptr[i]);
#pragma unroll
  for (int i = 0; i < 4; ++i) bv[i] = *(const uint4*)(bptr[i]);
#pragma unroll
  for (int i = 0; i < AU; ++i) ((uint4*)As[0])[au[i]] = av[i];
#pragma unroll
  for (int i = 0; i < 4; ++i) ((uint4*)Bs[0])[bu[i]] = bv[i];
  for (int kt = 0; kt < 16; ++kt) {
    __syncthreads();
    if (kt < 15) {
      int k0 = (kt + 1) * 64;
#pragma unroll
      for (int i = 0; i < AU; ++i) av[i] = *(const uint4*)(aptr[i] + k0);
#pragma unroll
      for (int i = 0; i < 4; ++i) bv[i] = *(const uint4*)(bptr[i] + k0);
    }
    int cur = kt & 1;
#pragma unroll
    for (int ks = 0; ks < 2; ++ks) {
      bf16x8 af[MI], bfr[2];
#pragma unroll
      for (int mi = 0; mi < MI; ++mi)
        af[mi] = ((const bf16x8*)As[cur])[lds_uT<TM>(mi * 16 + col, ks * 4 + quad)];
#pragma unroll
      for (int ni = 0; ni < 2; ++ni)
        bfr[ni] = ((const bf16x8*)Bs[cur])[lds_u128(wave * 32 + ni * 16 + col, ks * 4 + quad)];
#pragma unroll
      for (int mi = 0; mi < MI; ++mi)
#pragma unroll
        for (int ni = 0; ni < 2; ++ni)
          acc[mi][ni] = MFMA16(af[mi], bfr[ni], acc[mi][ni]);
    }
    if (kt < 15) {
      int nxt = cur ^ 1;
#pragma unroll
      for (int i = 0; i < AU; ++i) ((uint4*)As[nxt])[au[i]] = av[i];
#pragma unroll
      for (int i = 0; i < 4; ++i) ((uint4*)Bs[nxt])[bu[i]] = bv[i];
    }
  }
#pragma unroll
  for (int mi = 0; mi < MI; ++mi)
#pragma unroll
    for (int ni = 0; ni < 2; ++ni)
#pragma unroll
      for (int r = 0; r < 4; ++r) {
        int grow = bm * TM + mi * 16 + quad * 4 + r;
        int gcol = bn * 128 + wave * 32 + ni * 16 + col;
        float v = acc[mi][ni][r];
        size_t idx = (size_t)grow * 1024 + gcol;
        if constexpr (EP == EP_KV) {
          if (gcol < 1024) {
            // k -> (b,h,f,d): b=grow>>11, f=grow&2047, h=gcol>>6, d=gcol&63
            size_t ki = (((size_t)(grow >> 11) * 16 + (gcol >> 6)) * 2048 +
                         (grow & 2047)) * 64 + (gcol & 63);
            ((unsigned short*)out0)[ki] = f2bf(v);
          } else {
            ((unsigned short*)out1)[(size_t)grow * 1024 + gcol - 1024] = f2bf(v);
          }
        } else if constexpr (EP == EP_QUV) {
          ((unsigned short*)out0)[idx] = f2bf(v + auxA[gcol]);
          ((unsigned short*)out1)[idx] = f2bf(v + auxB[gcol]);
        } else if constexpr (EP == EP_QR) {
          // Qr -> (h,f,d): f=grow, h=gcol>>6, d=gcol&63
          size_t qi = ((size_t)(gcol >> 6) * 2048 + grow) * 64 + (gcol & 63);
          ((unsigned short*)out0)[qi] = f2bf(v);
        } else if constexpr (EP == EP_GELU_F32) {
          ((float*)out0)[idx] = gelu_f(v);
        } else if constexpr (EP == EP_GATE1) {
          float a = v + bias[gcol];
          float sg = 1.f / (1.f + __expf(-a));
          float g1 = auxA[idx] + sg * auxB[idx];
          ((float*)out0)[idx] = g1;
          ((unsigned short*)out1)[idx] = f2bf(g1);
        } else if constexpr (EP == EP_GELU_B_BF16) {
          ((unsigned short*)out0)[idx] = f2bf(gelu_f(v + bias[gcol]));
        } else if constexpr (EP == EP_GELU_B_F32) {
          ((float*)out0)[idx] = gelu_f(v + bias[gcol]);
        } else {  // EP_GATE2
          float a = v + bias[gcol];
          float sg = 1.f / (1.f + __expf(-a));
          ((float*)out0)[idx] = auxA[idx] + sg * auxB[idx];
        }
      }
}

// ---------------------------------------------------------------------------
// k_tr: v (b,f,h,d) bf16 -> vT (b,h,d,f) bf16.  grid (32 bh, 32 ftile).
// ---------------------------------------------------------------------------
__global__ __launch_bounds__(256) void k_tr(
    const unsigned short* __restrict__ v, unsigned short* __restrict__ vT) {
  __shared__ unsigned short tl[64][72];
  int bh = blockIdx.x, ft = blockIdx.y;
  int b = bh >> 4, h = bh & 15;
  int f0 = ft * 64;
  int tid = threadIdx.x;
  int fr = tid >> 2, c0 = (tid & 3) * 16;
  *(uint4*)&tl[fr][c0] =
      *(const uint4*)(v + ((size_t)(b * 2048 + f0 + fr)) * 1024 + h * 64 + c0);
  __syncthreads();
  int dr = tid >> 2, fc = (tid & 3) * 16;
  unsigned short* dst =
      vT + (((size_t)(b * 16 + h) * 64 + dr)) * 2048 + f0 + fc;
#pragma unroll
  for (int q = 0; q < 4; ++q) {
    ushort4 o;
    o.x = tl[fc + q * 4 + 0][dr];
    o.y = tl[fc + q * 4 + 1][dr];
    o.z = tl[fc + q * 4 + 2][dr];
    o.w = tl[fc + q * 4 + 3][dr];
    *(ushort4*)(dst + q * 4) = o;
  }
}

// ---------------------------------------------------------------------------
// Fused rel-pos attention, single pass + in-LDS normalize.
// grid (32 = B*H, 64 = S/16); block 256 = 4 waves (R2-benched shape: 2
// blocks/CU, best measured across R2/R7/R8 — bigger blocks only added
// serialization).  Wave w takes 32-col chunks {w, w+4, ...} of the ACTIVE
// range; chunk c+1's 14 loads issue before chunk c's compute (A/B register
// sets).
// COALESCED LAYOUTS (this round's lever): k is (b,h,f,d) and Qr is (h,f,d),
// so a chunk's K tile (32x64 bf16 = 4 KB) and each rel tile are SEQUENTIAL:
// one wave load instruction covers a contiguous 2 KB instead of gathering
// 16 rows 2 KB apart (16 cache lines/instr -> 1-2).  10 of 14 per-chunk
// loads coalesce; V keeps (b,h,d,f) for per-lane 16B contiguity in the PV
// fragment.
// Pass 1: p (bf16) into LDS tile Pb[16][2048+pad], rowsum + P@V in regs.
// Cross-wave reduce -> Rinv, O.  ao (bf16) + amax.
// Pass 2: stream Pb * rinv -> attn (fp32), regular coalesced f32x4 stores.
// ---------------------------------------------------------------------------
__global__ __launch_bounds__(256) void k_att(
    const unsigned short* __restrict__ qu, const unsigned short* __restrict__ qv,
    const unsigned short* __restrict__ kk, const unsigned short* __restrict__ vT,
    const unsigned short* __restrict__ Qr,
    float* __restrict__ attn, unsigned short* __restrict__ ao,
    float* __restrict__ amax) {
  __shared__ __align__(16) unsigned short Pb[16][2056];
  __shared__ __align__(16) float Ol[2][1024];
  __shared__ float Sl[4][16];
  __shared__ float Rinv[16];
  int tid = threadIdx.x, lane = tid & 63, wave = tid >> 6;
  int quad = lane >> 4, col = lane & 15;
  int bh = blockIdx.x, rt = blockIdx.y;
  int b = bh >> 4, h = bh & 15;
  int ri = rt * 16;

  bf16x8 quf[2], qvf[2];
  {
    const unsigned short* p0 = qu + ((size_t)(b * 1024 + ri + col)) * 1024 + h * 64 + quad * 8;
    quf[0] = *(const bf16x8*)p0;
    quf[1] = *(const bf16x8*)(p0 + 32);
    const unsigned short* p1 = qv + ((size_t)(b * 1024 + ri + col)) * 1024 + h * 64 + quad * 8;
    qvf[0] = *(const bf16x8*)p1;
    qvf[1] = *(const bf16x8*)(p1 + 32);
  }

  // Qr in (h,f,d): rows contiguous (64 bf16 apart)
  const unsigned short* qrbase = Qr + (size_t)h * 2048 * 64 + quad * 8;
  auto r_load = [&](int cbase, bf16x8& b0, bf16x8& b1) {
    int cr = cbase + col;
    cr = cr < 0 ? 0 : (cr > 2047 ? 2047 : cr);
    const unsigned short* p = qrbase + (size_t)cr * 64;
    b0 = *(const bf16x8*)p;
    b1 = *(const bf16x8*)(p + 32);
  };
  auto r_mm = [&](bf16x8 b0, bf16x8 b1) -> f32x4 {
    f32x4 z = {0.f, 0.f, 0.f, 0.f};
    z = MFMA16(qvf[0], b0, z);
    z = MFMA16(qvf[1], b1, z);
    return z;
  };

  // k in (b,h,f,d): rows contiguous (64 bf16 apart)
  const unsigned short* kbase = kk + ((size_t)(b * 16 + h)) * 2048 * 64 + quad * 8;
  const unsigned short* vbase = vT + ((size_t)((b * 16 + h) * 64)) * 2048;

  f32x4 o4[4] = {};
  f32x4 srow = {0.f, 0.f, 0.f, 0.f};
  f32x4 pm = {0.f, 0.f, 0.f, 0.f};
  int jmax = ri + 15 + 1024;
  int NA = (jmax >> 5) + 1;                 // active 32-col chunks (33..64)
  int myN = (NA - wave + 3) >> 2;           // chunks owned by this wave (>=8)

  // --- per-chunk loads: 6 rel (3 tiles) + 4 K + 4 V bf16x8 regs ---
  auto load_chunk = [&](int j0, int cw, bf16x8* rr, bf16x8* kr, bf16x8* vr) {
    r_load(cw, rr[0], rr[1]);
    r_load(cw + 16, rr[2], rr[3]);
    r_load(cw + 32, rr[4], rr[5]);
    const unsigned short* kp0 = kbase + (size_t)(j0 + col) * 64;
    const unsigned short* kp1 = kbase + (size_t)(j0 + 16 + col) * 64;
    kr[0] = *(const bf16x8*)kp0;
    kr[1] = *(const bf16x8*)(kp0 + 32);
    kr[2] = *(const bf16x8*)kp1;
    kr[3] = *(const bf16x8*)(kp1 + 32);
    int fb = j0 + quad * 8;
#pragma unroll
    for (int ni = 0; ni < 4; ++ni)
      vr[ni] = *(const bf16x8*)(vbase + (size_t)(ni * 16 + col) * 2048 + fb);
  };

  auto compute_chunk = [&](int j0, bf16x8* rr, bf16x8* kr, bf16x8* vr) {
    f32x4 R0 = r_mm(rr[0], rr[1]);
    f32x4 R1 = r_mm(rr[2], rr[3]);
    f32x4 R2 = r_mm(rr[4], rr[5]);
    f32x4 ac0 = {0.f, 0.f, 0.f, 0.f};
    ac0 = MFMA16(quf[0], kr[0], ac0);
    ac0 = MFMA16(quf[1], kr[1], ac0);
    f32x4 ac1 = {0.f, 0.f, 0.f, 0.f};
    ac1 = MFMA16(quf[0], kr[2], ac1);
    ac1 = MFMA16(quf[1], kr[3], ac1);
#pragma unroll
    for (int r = 0; r < 4; ++r) {
      int w = 15 + col - quad * 4 - r;
      int src = quad * 16 + (w & 15);
      float bd0 = __shfl(R0[r], src, 64);
      float bd1 = __shfl(R1[r], src, 64);
      float bd = (w < 16) ? bd0 : bd1;
      float sc = (ac0[r] + bd) * 0.03125f;
      int masked = (j0 + col) > (ri + quad * 4 + r + 1024);
      float p = masked ? 0.f : __expf(sc);
      srow[r] += p;
      pm[r] = fmaxf(pm[r], p);
      Pb[quad * 4 + r][j0 + col] = f2bf(p);
    }
#pragma unroll
    for (int r = 0; r < 4; ++r) {
      int w = 15 + col - quad * 4 - r;
      int src = quad * 16 + (w & 15);
      float bd0 = __shfl(R1[r], src, 64);
      float bd1 = __shfl(R2[r], src, 64);
      float bd = (w < 16) ? bd0 : bd1;
      float sc = (ac1[r] + bd) * 0.03125f;
      int masked = (j0 + 16 + col) > (ri + quad * 4 + r + 1024);
      float p = masked ? 0.f : __expf(sc);
      srow[r] += p;
      pm[r] = fmaxf(pm[r], p);
      Pb[quad * 4 + r][j0 + 16 + col] = f2bf(p);
    }
    asm volatile("s_waitcnt lgkmcnt(0)" ::: "memory");
    bf16x8 pf = *(const bf16x8*)&Pb[col][j0 + quad * 8];
#pragma unroll
    for (int ni = 0; ni < 4; ++ni) o4[ni] = MFMA16(pf, vr[ni], o4[ni]);
  };

  {
    // two named register sets -> static indexing, no scratch (rule #20)
    bf16x8 Ar[6], Ak[4], Av[4], Br[6], Bk[4], Bv[4];
    int j0 = wave << 5;
    int cw = 1008 - ri + j0;
    load_chunk(j0, cw, Ar, Ak, Av);
    int i = 0;
    while (true) {
      if (i + 1 < myN) load_chunk(j0 + 128, cw + 128, Br, Bk, Bv);
      compute_chunk(j0, Ar, Ak, Av);
      ++i; j0 += 128; cw += 128;
      if (i >= myN) break;
      if (i + 1 < myN) load_chunk(j0 + 128, cw + 128, Ar, Ak, Av);
      compute_chunk(j0, Br, Bk, Bv);
      ++i; j0 += 128; cw += 128;
      if (i >= myN) break;
    }
  }

  // stripe row-sums / row-max (reduce across the 16 col lanes of each quad)
#pragma unroll
  for (int r = 0; r < 4; ++r) {
    float v = srow[r], m = pm[r];
    v += __shfl_xor(v, 1, 64);  m = fmaxf(m, __shfl_xor(m, 1, 64));
    v += __shfl_xor(v, 2, 64);  m = fmaxf(m, __shfl_xor(m, 2, 64));
    v += __shfl_xor(v, 4, 64);  m = fmaxf(m, __shfl_xor(m, 4, 64));
    v += __shfl_xor(v, 8, 64);  m = fmaxf(m, __shfl_xor(m, 8, 64));
    srow[r] = v; pm[r] = m;
  }
  if (col == 0) {
#pragma unroll
    for (int r = 0; r < 4; ++r) Sl[wave][quad * 4 + r] = srow[r];
  }
  if (wave >= 2) {
#pragma unroll
    for (int ni = 0; ni < 4; ++ni)
#pragma unroll
      for (int r = 0; r < 4; ++r)
        Ol[wave - 2][(quad * 4 + r) * 64 + ni * 16 + col] = o4[ni][r];
  }
  __syncthreads();
  if (tid < 16) {
    float rv = 1.f / (Sl[0][tid] + Sl[1][tid] + Sl[2][tid] + Sl[3][tid]);
    Rinv[tid] = rv;
  }
  if (wave < 2) {
#pragma unroll
    for (int ni = 0; ni < 4; ++ni)
#pragma unroll
      for (int r = 0; r < 4; ++r) {
        int ix = (quad * 4 + r) * 64 + ni * 16 + col;
        o4[ni][r] += Ol[wave][ix];
        if (wave == 1) Ol[1][ix] = o4[ni][r];
      }
  }
  __syncthreads();
  if (wave == 0) {
#pragma unroll
    for (int ni = 0; ni < 4; ++ni)
#pragma unroll
      for (int r = 0; r < 4; ++r) {
        int ix = (quad * 4 + r) * 64 + ni * 16 + col;
        o4[ni][r] += Ol[1][ix];
        Ol[0][ix] = o4[ni][r];
      }
  }
  __syncthreads();
  {
    int row = tid >> 4, d0 = (tid & 15) << 2;
    float4 ov = *(const float4*)&Ol[0][row * 64 + d0];
    float rv = Rinv[row];
    ushort4 o;
    o.x = f2bf(ov.x * rv); o.y = f2bf(ov.y * rv);
    o.z = f2bf(ov.z * rv); o.w = f2bf(ov.w * rv);
    *(ushort4*)(ao + ((size_t)(b * 1024 + ri + row)) * 1024 + h * 64 + d0) = o;
  }
  // per-(b,h) max of normalized p
  float pmax = 0.f;
#pragma unroll
  for (int r = 0; r < 4; ++r) pmax = fmaxf(pmax, pm[r] * Rinv[quad * 4 + r]);
  pmax = fmaxf(pmax, __shfl_xor(pmax, 16, 64));
  pmax = fmaxf(pmax, __shfl_xor(pmax, 32, 64));
  if (lane == 0) atomicMax((int*)(amax + bh), __float_as_int(pmax));

  // ---- pass 2: normalized attn write (regular coalesced f32x4, mask -> 0) --
  {
    float* abase = attn + ((size_t)bh * 1024 + ri) * 2048;
#pragma unroll 4
    for (int it = 0; it < 32; ++it) {
      int idx = it * 256 + tid;      // 8192 f32x4 units = 16 rows x 512
      int row = idx >> 9;
      int j = (idx & 511) << 2;
      float rv = Rinv[row];
      int lim = ri + row + 1024;
      ushort4 p4 = *(const ushort4*)&Pb[row][j];
      f32x4 o;
      o[0] = (j + 0 <= lim) ? bf2f(p4.x) * rv : 0.f;
      o[1] = (j + 1 <= lim) ? bf2f(p4.y) * rv : 0.f;
      o[2] = (j + 2 <= lim) ? bf2f(p4.z) * rv : 0.f;
      o[3] = (j + 3 <= lim) ? bf2f(p4.w) * rv : 0.f;
      *(f32x4*)(abase + (size_t)row * 2048 + j) = o;
    }
  }
}

// ---------------------------------------------------------------------------
__global__ void k_loss(const float* __restrict__ amax, float* __restrict__ out) {
  int l = threadIdx.x;
  float v = (l < 32) ? amax[l] : 0.f;
  v += __shfl_xor(v, 1, 64);
  v += __shfl_xor(v, 2, 64);
  v += __shfl_xor(v, 4, 64);
  v += __shfl_xor(v, 8, 64);
  v += __shfl_xor(v, 16, 64);
  v += __shfl_xor(v, 32, 64);
  if (l == 0) out[0] = v * (1.f / 32.f);
}

// ---------------------------------------------------------------------------
extern "C" void kernel_launch(void* const* d_in, const int* in_sizes, int n_in,
                              void* d_out, int out_size, void* d_ws, size_t ws_size,
                              hipStream_t stream) {
  (void)in_sizes; (void)n_in; (void)out_size; (void)ws_size;
  const float* inputs = (const float*)d_in[0];
  const float* mem    = (const float*)d_in[1];
  const float* rel    = (const float*)d_in[2];
  const float* ln1g   = (const float*)d_in[4];
  const float* ln1b   = (const float*)d_in[5];
  const float* wq     = (const float*)d_in[6];
  const float* wke    = (const float*)d_in[7];
  const float* wkr    = (const float*)d_in[8];
  const float* wv     = (const float*)d_in[9];
  const float* wf     = (const float*)d_in[10];
  const float* up     = (const float*)d_in[11];
  const float* vp     = (const float*)d_in[12];
  const float* ln2g   = (const float*)d_in[13];
  const float* ln2b   = (const float*)d_in[14];
  const float* w1     = (const float*)d_in[15];
  const float* b1     = (const float*)d_in[16];
  const float* w2     = (const float*)d_in[17];
  const float* b2     = (const float*)d_in[18];
  const float* wg1    = (const float*)d_in[19];
  const float* bg1    = (const float*)d_in[20];
  const float* wg2    = (const float*)d_in[21];
  const float* bg2    = (const float*)d_in[22];

  char* ws = (char*)d_ws;
  unsigned short* wT  = (unsigned short*)(ws);              // 18 MB (9 x 1Mel)
  unsigned short* xt  = (unsigned short*)(ws + 18874368);   // 8 MB
  unsigned short* inb = (unsigned short*)(ws + 27262976);   // 4 MB
  unsigned short* reb = (unsigned short*)(ws + 31457280);   // 4 MB
  unsigned short* kb  = (unsigned short*)(ws + 35651584);   // 8 MB (b,h,f,d)
  unsigned short* vTb = (unsigned short*)(ws + 44040192);   // 8 MB
  unsigned short* qub = (unsigned short*)(ws + 52428800);   // 4 MB
  unsigned short* qvb = (unsigned short*)(ws + 56623104);   // 4 MB
  unsigned short* Qrb = (unsigned short*)(ws + 60817408);   // 4 MB (h,f,d)
  float* amax         = (float*)(ws + 65011712);            // 128 B
  // aliases onto dead buffers:
  unsigned short* vb = qub;          // v row-major, dead after k_tr (8 MB)
  float* rmha = (float*)xt;
  unsigned short* aob = reb;
  float* g1f = (float*)kb;
  float* h2f = (float*)vTb;
  unsigned short* g1b = qub;
  unsigned short* h0b = qvb;
  unsigned short* h1b = Qrb;

  float* outp  = (float*)d_out;
  float* attnp = outp + 2097152;
  float* lossp = outp + 69206016;

  W9 wp;
  wp.p[0] = wq;  wp.p[1] = wke; wp.p[2] = wv;  wp.p[3] = wkr; wp.p[4] = wf;
  wp.p[5] = w1;  wp.p[6] = w2;  wp.p[7] = wg1; wp.p[8] = wg2;

  k_init<<<8448, 256, 0, stream>>>(inputs, mem, rel, ln1g, ln1b, wp,
                                   xt, inb, reb, wT, amax);
  // k|v fused: (B*F,1024) @ [wke|wv]^T  (N=2048); k -> (b,h,f,d), v row-major
  k_gemm<EP_KV, 64><<<dim3(16, 64), 256, 0, stream>>>(
      xt, wT + (1u << 20), 0, 0, nullptr, nullptr, nullptr, kb, vb);
  // vT (b,h,d,f) from v (b,f,h,d)
  k_tr<<<dim3(32, 32), 256, 0, stream>>>(vb, vTb);
  // q -> qu = q+u_param, qv = q+v_param  (A rows = x_tilde[:, -S:]) — clobbers vb
  k_gemm<EP_QUV, 32><<<dim3(8, 64), 256, 0, stream>>>(
      xt, wT, 1024, 1024, nullptr, up, vp, qub, qvb);
  // Qr = rel_enc @ wkr -> (h,f,d)
  k_gemm<EP_QR, 32><<<dim3(8, 64), 256, 0, stream>>>(
      reb, wT + 3u * (1u << 20), 0, 0, nullptr, nullptr, nullptr, Qrb, nullptr);
  // attention: normalized attn directly (in-LDS p tile), ao, amax
  k_att<<<dim3(32, 64), 256, 0, stream>>>(qub, qvb, kb, vTb, Qrb,
                                          attnp, aob, amax);
  // rmha = gelu(ao @ wf)
  k_gemm<EP_GELU_F32, 32><<<dim3(8, 64), 256, 0, stream>>>(
      aob, wT + 4u * (1u << 20), 0, 0, nullptr, nullptr, nullptr, rmha, nullptr);
  // g1 = inputs + sigmoid(inputs@wg1 + bg1) * rmha
  k_gemm<EP_GATE1, 32><<<dim3(8, 64), 256, 0, stream>>>(
      inb, wT + 7u * (1u << 20), 0, 0, bg1, inputs, rmha, g1f, g1b);
  // h0 = LN2(g1)
  k_ln<<<2048, 256, 0, stream>>>(g1f, ln2g, ln2b, h0b);
  // h1 = gelu(h0@w1 + b1)
  k_gemm<EP_GELU_B_BF16, 32><<<dim3(8, 64), 256, 0, stream>>>(
      h0b, wT + 5u * (1u << 20), 0, 0, b1, nullptr, nullptr, h1b, nullptr);
  // h2 = gelu(h1@w2 + b2)
  k_gemm<EP_GELU_B_F32, 32><<<dim3(8, 64), 256, 0, stream>>>(
      h1b, wT + 6u * (1u << 20), 0, 0, b2, nullptr, nullptr, h2f, nullptr);
  // out = g1 + sigmoid(g1@wg2 + bg2) * h2
  k_gemm<EP_GATE2, 32><<<dim3(8, 64), 256, 0, stream>>>(
      g1b, wT + 8u * (1u << 20), 0, 0, bg2, g1f, h2f, outp, nullptr);
  k_loss<<<1, 64, 0, stream>>>(amax, lossp);
}

// Round 11
// 642.480 us; speedup vs baseline: 1.2698x; 1.1064x over previous
//
#include <hip/hip_runtime.h>
#include <hip/hip_bf16.h>

// ---------------------------------------------------------------------------
// Transformer-XL block on MI355X.  Shapes: B=2, S=1024, M=1024, F=2048,
// D=1024, H=16, dh=64.  Outputs: out[2M] fp32, attn[2*16*1024*2048] fp32,
// loss[1] fp32.
// ---------------------------------------------------------------------------

typedef __attribute__((ext_vector_type(8))) short bf16x8;
typedef __attribute__((ext_vector_type(4))) float f32x4;

#define MFMA16(a, b, c) __builtin_amdgcn_mfma_f32_16x16x32_bf16((a), (b), (c), 0, 0, 0)

__device__ __forceinline__ unsigned short f2bf(float f) {
  union { __hip_bfloat16 h; unsigned short u; } cv;
  cv.h = __float2bfloat16(f);
  return cv.u;
}

__device__ __forceinline__ float bf2f(unsigned short u) {
  return __uint_as_float((unsigned)u << 16);
}

__device__ __forceinline__ float gelu_f(float x) {
  return 0.5f * x * (1.f + erff(x * 0.70710678118654752f));
}

struct W9 { const float* p[9]; };

// ---------------------------------------------------------------------------
// k_init: [0,4096): LN(concat(mem,inputs))->xt bf16, inputs->inb bf16;
// [4096,6144): rel_enc->reb; [6144,8448): weights -> wT bf16 transposed.
// ---------------------------------------------------------------------------
__global__ __launch_bounds__(256) void k_init(
    const float* __restrict__ inputs, const float* __restrict__ mem,
    const float* __restrict__ rel_enc, const float* __restrict__ g1n,
    const float* __restrict__ b1n, W9 wp,
    unsigned short* __restrict__ xt, unsigned short* __restrict__ inb,
    unsigned short* __restrict__ reb, unsigned short* __restrict__ wT,
    float* __restrict__ amax) {
  int bid = blockIdx.x, tid = threadIdx.x;
  if (bid == 0 && tid < 32) amax[tid] = 0.f;
  if (bid < 4096) {
    __shared__ float red[8];
    int b = bid >> 11, fi = bid & 2047;
    const float* src = (fi < 1024)
        ? (mem + ((size_t)(b * 1024 + fi)) * 1024)
        : (inputs + ((size_t)(b * 1024 + fi - 1024)) * 1024);
    float4 x = ((const float4*)src)[tid];
    float s = x.x + x.y + x.z + x.w;
    float ss = x.x * x.x + x.y * x.y + x.z * x.z + x.w * x.w;
#pragma unroll
    for (int m = 32; m > 0; m >>= 1) {
      s += __shfl_down(s, m, 64);
      ss += __shfl_down(ss, m, 64);
    }
    int w = tid >> 6;
    if ((tid & 63) == 0) { red[w] = s; red[4 + w] = ss; }
    __syncthreads();
    s = red[0] + red[1] + red[2] + red[3];
    ss = red[4] + red[5] + red[6] + red[7];
    float mu = s * (1.f / 1024.f);
    float inv = rsqrtf(ss * (1.f / 1024.f) - mu * mu + 1e-5f);
    float4 g = ((const float4*)g1n)[tid];
    float4 bb = ((const float4*)b1n)[tid];
    ushort4 o;
    o.x = f2bf((x.x - mu) * inv * g.x + bb.x);
    o.y = f2bf((x.y - mu) * inv * g.y + bb.y);
    o.z = f2bf((x.z - mu) * inv * g.z + bb.z);
    o.w = f2bf((x.w - mu) * inv * g.w + bb.w);
    ((ushort4*)(xt + (size_t)bid * 1024))[tid] = o;
    if (fi >= 1024) {
      ushort4 r4;
      r4.x = f2bf(x.x); r4.y = f2bf(x.y); r4.z = f2bf(x.z); r4.w = f2bf(x.w);
      ((ushort4*)(inb + ((size_t)(b * 1024 + fi - 1024)) * 1024))[tid] = r4;
    }
  } else if (bid < 6144) {
    int r = bid - 4096;
    float4 x = ((const float4*)(rel_enc + (size_t)r * 1024))[tid];
    ushort4 o;
    o.x = f2bf(x.x); o.y = f2bf(x.y); o.z = f2bf(x.z); o.w = f2bf(x.w);
    ((ushort4*)(reb + (size_t)r * 1024))[tid] = o;
  } else {
    __shared__ float tl[64][65];
    int idx = bid - 6144;
    int m = idx >> 8;
    int t = idx & 255;
    int k0 = (t >> 4) << 6, n0 = (t & 15) << 6;
    const float* srcw = wp.p[m];
    int kr = tid >> 4, nc = (tid & 15) << 2;
#pragma unroll
    for (int i = 0; i < 4; ++i) {
      int krow = i * 16 + kr;
      float4 v = *(const float4*)(srcw + (size_t)(k0 + krow) * 1024 + n0 + nc);
      tl[nc + 0][krow] = v.x;
      tl[nc + 1][krow] = v.y;
      tl[nc + 2][krow] = v.z;
      tl[nc + 3][krow] = v.w;
    }
    __syncthreads();
    int n = tid >> 2, kc0 = (tid & 3) << 4;
    unsigned short* dst = wT + ((size_t)m << 20) + (size_t)(n0 + n) * 1024 + k0 + kc0;
#pragma unroll
    for (int q = 0; q < 4; ++q) {
      ushort4 o;
      o.x = f2bf(tl[n][kc0 + q * 4 + 0]);
      o.y = f2bf(tl[n][kc0 + q * 4 + 1]);
      o.z = f2bf(tl[n][kc0 + q * 4 + 2]);
      o.w = f2bf(tl[n][kc0 + q * 4 + 3]);
      *(ushort4*)(dst + q * 4) = o;
    }
  }
}

// ---------------------------------------------------------------------------
// k_ln: LayerNorm rows of fp32 (2048 x 1024) -> bf16
// ---------------------------------------------------------------------------
__global__ __launch_bounds__(256) void k_ln(
    const float* __restrict__ xin, const float* __restrict__ g1n,
    const float* __restrict__ b1n, unsigned short* __restrict__ outb) {
  __shared__ float red[8];
  int bid = blockIdx.x, tid = threadIdx.x;
  const float* src = xin + (size_t)bid * 1024;
  float4 x = ((const float4*)src)[tid];
  float s = x.x + x.y + x.z + x.w;
  float ss = x.x * x.x + x.y * x.y + x.z * x.z + x.w * x.w;
#pragma unroll
  for (int m = 32; m > 0; m >>= 1) {
    s += __shfl_down(s, m, 64);
    ss += __shfl_down(ss, m, 64);
  }
  int w = tid >> 6;
  if ((tid & 63) == 0) { red[w] = s; red[4 + w] = ss; }
  __syncthreads();
  s = red[0] + red[1] + red[2] + red[3];
  ss = red[4] + red[5] + red[6] + red[7];
  float mu = s * (1.f / 1024.f);
  float inv = rsqrtf(ss * (1.f / 1024.f) - mu * mu + 1e-5f);
  float4 g = ((const float4*)g1n)[tid];
  float4 bb = ((const float4*)b1n)[tid];
  ushort4 o;
  o.x = f2bf((x.x - mu) * inv * g.x + bb.x);
  o.y = f2bf((x.y - mu) * inv * g.y + bb.y);
  o.z = f2bf((x.z - mu) * inv * g.z + bb.z);
  o.w = f2bf((x.w - mu) * inv * g.w + bb.w);
  ((ushort4*)(outb + (size_t)bid * 1024))[tid] = o;
}

// ---------------------------------------------------------------------------
// GEMM (R9-proven): C[M,Nt] = A[M,1024] @ Wt[Nt,1024]^T, tile TM x 128,
// BK=64, 4 waves split the 128-col dim.  Double-buffered LDS.
// EP_KV writes k in (b,h,f,d); EP_QR writes Qr in (h,f,d).
// ---------------------------------------------------------------------------
__device__ __forceinline__ int lds_u128(int r, int g) {
  return g * 128 + (r & ~7) + ((r ^ g) & 7);
}
template <int TM>
__device__ __forceinline__ int lds_uT(int r, int g) {
  return g * TM + (r & ~7) + ((r ^ g) & 7);
}
__device__ __forceinline__ int lds_u64s(int r, int g) {
  return g * 64 + (r & ~7) + ((r ^ g) & 7);
}

enum { EP_KV = 0, EP_QUV, EP_QR, EP_GELU_F32, EP_GATE1,
       EP_GELU_B_BF16, EP_GELU_B_F32, EP_GATE2 };

template <int EP, int TM>
__global__ __launch_bounds__(256, TM == 32 ? 4 : 3) void k_gemm(
    const unsigned short* __restrict__ A, const unsigned short* __restrict__ Bw,
    int arow_add, int arow_mul,
    const float* __restrict__ bias, const float* __restrict__ auxA,
    const float* __restrict__ auxB, void* __restrict__ out0,
    void* __restrict__ out1) {
  constexpr int MI = TM / 16;
  constexpr int AU = TM / 32;
  __shared__ __align__(16) unsigned short As[2][TM * 64];
  __shared__ __align__(16) unsigned short Bs[2][128 * 64];
  int tid = threadIdx.x;
  int lane = tid & 63, wave = tid >> 6;
  int quad = lane >> 4, col = lane & 15;
  int bm = blockIdx.y, bn = blockIdx.x;
  f32x4 acc[MI][2] = {};
  int str = tid >> 3, stg = tid & 7;
  const unsigned short* aptr[AU];
  int au[AU];
  const unsigned short* bptr[4];
  int bu[4];
#pragma unroll
  for (int i = 0; i < AU; ++i) {
    int r = str + 32 * i;
    int gr = bm * TM + r;
    int ar = gr + arow_add + (gr >> 10) * arow_mul;
    aptr[i] = A + (size_t)ar * 1024 + stg * 8;
    au[i] = lds_uT<TM>(r, stg);
  }
#pragma unroll
  for (int i = 0; i < 4; ++i) {
    int r = str + 32 * i;
    bptr[i] = Bw + (size_t)(bn * 128 + r) * 1024 + stg * 8;
    bu[i] = lds_u128(r, stg);
  }
  uint4 av[AU], bv[4];
#pragma unroll
  for (int i = 0; i < AU; ++i) av[i] = *(const uint4*)(aptr[i]);
#pragma unroll
  for (int i = 0; i < 4; ++i) bv[i] = *(const uint4*)(bptr[i]);
#pragma unroll
  for (int i = 0; i < AU; ++i) ((uint4*)As[0])[au[i]] = av[i];
#pragma unroll
  for (int i = 0; i < 4; ++i) ((uint4*)Bs[0])[bu[i]] = bv[i];
  for (int kt = 0; kt < 16; ++kt) {
    __syncthreads();
    if (kt < 15) {
      int k0 = (kt + 1) * 64;
#pragma unroll
      for (int i = 0; i < AU; ++i) av[i] = *(const uint4*)(aptr[i] + k0);
#pragma unroll
      for (int i = 0; i < 4; ++i) bv[i] = *(const uint4*)(bptr[i] + k0);
    }
    int cur = kt & 1;
#pragma unroll
    for (int ks = 0; ks < 2; ++ks) {
      bf16x8 af[MI], bfr[2];
#pragma unroll
      for (int mi = 0; mi < MI; ++mi)
        af[mi] = ((const bf16x8*)As[cur])[lds_uT<TM>(mi * 16 + col, ks * 4 + quad)];
#pragma unroll
      for (int ni = 0; ni < 2; ++ni)
        bfr[ni] = ((const bf16x8*)Bs[cur])[lds_u128(wave * 32 + ni * 16 + col, ks * 4 + quad)];
#pragma unroll
      for (int mi = 0; mi < MI; ++mi)
#pragma unroll
        for (int ni = 0; ni < 2; ++ni)
          acc[mi][ni] = MFMA16(af[mi], bfr[ni], acc[mi][ni]);
    }
    if (kt < 15) {
      int nxt = cur ^ 1;
#pragma unroll
      for (int i = 0; i < AU; ++i) ((uint4*)As[nxt])[au[i]] = av[i];
#pragma unroll
      for (int i = 0; i < 4; ++i) ((uint4*)Bs[nxt])[bu[i]] = bv[i];
    }
  }
#pragma unroll
  for (int mi = 0; mi < MI; ++mi)
#pragma unroll
    for (int ni = 0; ni < 2; ++ni)
#pragma unroll
      for (int r = 0; r < 4; ++r) {
        int grow = bm * TM + mi * 16 + quad * 4 + r;
        int gcol = bn * 128 + wave * 32 + ni * 16 + col;
        float v = acc[mi][ni][r];
        size_t idx = (size_t)grow * 1024 + gcol;
        if constexpr (EP == EP_KV) {
          if (gcol < 1024) {
            // k -> (b,h,f,d): b=grow>>11, f=grow&2047, h=gcol>>6, d=gcol&63
            size_t ki = (((size_t)(grow >> 11) * 16 + (gcol >> 6)) * 2048 +
                         (grow & 2047)) * 64 + (gcol & 63);
            ((unsigned short*)out0)[ki] = f2bf(v);
          } else {
            ((unsigned short*)out1)[(size_t)grow * 1024 + gcol - 1024] = f2bf(v);
          }
        } else if constexpr (EP == EP_QUV) {
          ((unsigned short*)out0)[idx] = f2bf(v + auxA[gcol]);
          ((unsigned short*)out1)[idx] = f2bf(v + auxB[gcol]);
        } else if constexpr (EP == EP_QR) {
          // Qr -> (h,f,d): f=grow, h=gcol>>6, d=gcol&63
          size_t qi = ((size_t)(gcol >> 6) * 2048 + grow) * 64 + (gcol & 63);
          ((unsigned short*)out0)[qi] = f2bf(v);
        } else if constexpr (EP == EP_GELU_F32) {
          ((float*)out0)[idx] = gelu_f(v);
        } else if constexpr (EP == EP_GATE1) {
          float a = v + bias[gcol];
          float sg = 1.f / (1.f + __expf(-a));
          float g1 = auxA[idx] + sg * auxB[idx];
          ((float*)out0)[idx] = g1;
          ((unsigned short*)out1)[idx] = f2bf(g1);
        } else if constexpr (EP == EP_GELU_B_BF16) {
          ((unsigned short*)out0)[idx] = f2bf(gelu_f(v + bias[gcol]));
        } else if constexpr (EP == EP_GELU_B_F32) {
          ((float*)out0)[idx] = gelu_f(v + bias[gcol]);
        } else {  // EP_GATE2
          float a = v + bias[gcol];
          float sg = 1.f / (1.f + __expf(-a));
          ((float*)out0)[idx] = auxA[idx] + sg * auxB[idx];
        }
      }
}

// ---------------------------------------------------------------------------
// k_gemm2: TN=64 occupancy experiment, TAIL GEMMs ONLY (R10 post-mortem:
// all-at-once rewrite NaN'd with no isolation; this is the minimal,
// hand-enumerable variant).  TM=32, TN=64, grid (16,64) = 1024 blocks =
// 4 blocks/CU (LDS 24 KB).  No min-blocks bound (avoids VGPR-cap hazards).
// Per thread: 1 A-store (str 0..31 x stg 0..7 bijective), 2 B-stores
// (rows 0..63 bijective).  Per wave: 16 output cols (wave*16+col), acc[2]
// over 32 rows.  Accumulation order identical to k_gemm -> bitwise-same.
// ---------------------------------------------------------------------------
template <int EP>
__global__ __launch_bounds__(256) void k_gemm2(
    const unsigned short* __restrict__ A, const unsigned short* __restrict__ Bw,
    const float* __restrict__ bias, const float* __restrict__ auxA,
    const float* __restrict__ auxB, void* __restrict__ out0,
    void* __restrict__ out1) {
  __shared__ __align__(16) unsigned short As[2][32 * 64];
  __shared__ __align__(16) unsigned short Bs[2][64 * 64];
  int tid = threadIdx.x;
  int lane = tid & 63, wave = tid >> 6;
  int quad = lane >> 4, col = lane & 15;
  int bm = blockIdx.y, bn = blockIdx.x;
  f32x4 acc[2] = {};
  int str = tid >> 3, stg = tid & 7;
  const unsigned short* aptr = A + (size_t)(bm * 32 + str) * 1024 + stg * 8;
  int au = lds_uT<32>(str, stg);
  const unsigned short* bptr0 = Bw + (size_t)(bn * 64 + str) * 1024 + stg * 8;
  const unsigned short* bptr1 = bptr0 + (size_t)32 * 1024;
  int bu0 = lds_u64s(str, stg);
  int bu1 = lds_u64s(str + 32, stg);
  uint4 av = *(const uint4*)aptr;
  uint4 bv0 = *(const uint4*)bptr0;
  uint4 bv1 = *(const uint4*)bptr1;
  ((uint4*)As[0])[au] = av;
  ((uint4*)Bs[0])[bu0] = bv0;
  ((uint4*)Bs[0])[bu1] = bv1;
  for (int kt = 0; kt < 16; ++kt) {
    __syncthreads();
    if (kt < 15) {
      int k0 = (kt + 1) * 64;
      av = *(const uint4*)(aptr + k0);
      bv0 = *(const uint4*)(bptr0 + k0);
      bv1 = *(const uint4*)(bptr1 + k0);
    }
    int cur = kt & 1;
#pragma unroll
    for (int ks = 0; ks < 2; ++ks) {
      bf16x8 af0 = ((const bf16x8*)As[cur])[lds_uT<32>(col, ks * 4 + quad)];
      bf16x8 af1 = ((const bf16x8*)As[cur])[lds_uT<32>(16 + col, ks * 4 + quad)];
      bf16x8 bf0 = ((const bf16x8*)Bs[cur])[lds_u64s(wave * 16 + col, ks * 4 + quad)];
      acc[0] = MFMA16(af0, bf0, acc[0]);
      acc[1] = MFMA16(af1, bf0, acc[1]);
    }
    if (kt < 15) {
      int nxt = cur ^ 1;
      ((uint4*)As[nxt])[au] = av;
      ((uint4*)Bs[nxt])[bu0] = bv0;
      ((uint4*)Bs[nxt])[bu1] = bv1;
    }
  }
#pragma unroll
  for (int mi = 0; mi < 2; ++mi)
#pragma unroll
    for (int r = 0; r < 4; ++r) {
      int grow = bm * 32 + mi * 16 + quad * 4 + r;
      int gcol = bn * 64 + wave * 16 + col;
      float v = acc[mi][r];
      size_t idx = (size_t)grow * 1024 + gcol;
      if constexpr (EP == EP_GELU_F32) {
        ((float*)out0)[idx] = gelu_f(v);
      } else if constexpr (EP == EP_GATE1) {
        float a = v + bias[gcol];
        float sg = 1.f / (1.f + __expf(-a));
        float g1 = auxA[idx] + sg * auxB[idx];
        ((float*)out0)[idx] = g1;
        ((unsigned short*)out1)[idx] = f2bf(g1);
      } else if constexpr (EP == EP_GELU_B_BF16) {
        ((unsigned short*)out0)[idx] = f2bf(gelu_f(v + bias[gcol]));
      } else if constexpr (EP == EP_GELU_B_F32) {
        ((float*)out0)[idx] = gelu_f(v + bias[gcol]);
      } else {  // EP_GATE2
        float a = v + bias[gcol];
        float sg = 1.f / (1.f + __expf(-a));
        ((float*)out0)[idx] = auxA[idx] + sg * auxB[idx];
      }
    }
}

// ---------------------------------------------------------------------------
// k_tr: v (b,f,h,d) bf16 -> vT (b,h,d,f) bf16.  grid (32 bh, 32 ftile).
// ---------------------------------------------------------------------------
__global__ __launch_bounds__(256) void k_tr(
    const unsigned short* __restrict__ v, unsigned short* __restrict__ vT) {
  __shared__ unsigned short tl[64][72];
  int bh = blockIdx.x, ft = blockIdx.y;
  int b = bh >> 4, h = bh & 15;
  int f0 = ft * 64;
  int tid = threadIdx.x;
  int fr = tid >> 2, c0 = (tid & 3) * 16;
  *(uint4*)&tl[fr][c0] =
      *(const uint4*)(v + ((size_t)(b * 2048 + f0 + fr)) * 1024 + h * 64 + c0);
  __syncthreads();
  int dr = tid >> 2, fc = (tid & 3) * 16;
  unsigned short* dst =
      vT + (((size_t)(b * 16 + h) * 64 + dr)) * 2048 + f0 + fc;
#pragma unroll
  for (int q = 0; q < 4; ++q) {
    ushort4 o;
    o.x = tl[fc + q * 4 + 0][dr];
    o.y = tl[fc + q * 4 + 1][dr];
    o.z = tl[fc + q * 4 + 2][dr];
    o.w = tl[fc + q * 4 + 3][dr];
    *(ushort4*)(dst + q * 4) = o;
  }
}

// ---------------------------------------------------------------------------
// Fused rel-pos attention (R9-benched version, unchanged).
// grid (32 = B*H, 64 = S/16); block 256 = 4 waves, 2 blocks/CU.
// k in (b,h,f,d), Qr in (h,f,d) (contiguous rows); V in (b,h,d,f).
// Pass 1: p (bf16) into LDS tile Pb[16][2048+pad], rowsum + P@V in regs.
// Cross-wave reduce -> Rinv, O.  ao (bf16) + amax.
// Pass 2: stream Pb * rinv -> attn (fp32), regular coalesced f32x4 stores.
// ---------------------------------------------------------------------------
__global__ __launch_bounds__(256) void k_att(
    const unsigned short* __restrict__ qu, const unsigned short* __restrict__ qv,
    const unsigned short* __restrict__ kk, const unsigned short* __restrict__ vT,
    const unsigned short* __restrict__ Qr,
    float* __restrict__ attn, unsigned short* __restrict__ ao,
    float* __restrict__ amax) {
  __shared__ __align__(16) unsigned short Pb[16][2056];
  __shared__ __align__(16) float Ol[2][1024];
  __shared__ float Sl[4][16];
  __shared__ float Rinv[16];
  int tid = threadIdx.x, lane = tid & 63, wave = tid >> 6;
  int quad = lane >> 4, col = lane & 15;
  int bh = blockIdx.x, rt = blockIdx.y;
  int b = bh >> 4, h = bh & 15;
  int ri = rt * 16;

  bf16x8 quf[2], qvf[2];
  {
    const unsigned short* p0 = qu + ((size_t)(b * 1024 + ri + col)) * 1024 + h * 64 + quad * 8;
    quf[0] = *(const bf16x8*)p0;
    quf[1] = *(const bf16x8*)(p0 + 32);
    const unsigned short* p1 = qv + ((size_t)(b * 1024 + ri + col)) * 1024 + h * 64 + quad * 8;
    qvf[0] = *(const bf16x8*)p1;
    qvf[1] = *(const bf16x8*)(p1 + 32);
  }

  // Qr in (h,f,d): rows contiguous (64 bf16 apart)
  const unsigned short* qrbase = Qr + (size_t)h * 2048 * 64 + quad * 8;
  auto r_load = [&](int cbase, bf16x8& b0, bf16x8& b1) {
    int cr = cbase + col;
    cr = cr < 0 ? 0 : (cr > 2047 ? 2047 : cr);
    const unsigned short* p = qrbase + (size_t)cr * 64;
    b0 = *(const bf16x8*)p;
    b1 = *(const bf16x8*)(p + 32);
  };
  auto r_mm = [&](bf16x8 b0, bf16x8 b1) -> f32x4 {
    f32x4 z = {0.f, 0.f, 0.f, 0.f};
    z = MFMA16(qvf[0], b0, z);
    z = MFMA16(qvf[1], b1, z);
    return z;
  };

  // k in (b,h,f,d): rows contiguous (64 bf16 apart)
  const unsigned short* kbase = kk + ((size_t)(b * 16 + h)) * 2048 * 64 + quad * 8;
  const unsigned short* vbase = vT + ((size_t)((b * 16 + h) * 64)) * 2048;

  f32x4 o4[4] = {};
  f32x4 srow = {0.f, 0.f, 0.f, 0.f};
  f32x4 pm = {0.f, 0.f, 0.f, 0.f};
  int jmax = ri + 15 + 1024;
  int NA = (jmax >> 5) + 1;                 // active 32-col chunks (33..64)
  int myN = (NA - wave + 3) >> 2;           // chunks owned by this wave (>=8)

  // --- per-chunk loads: 6 rel (3 tiles) + 4 K + 4 V bf16x8 regs ---
  auto load_chunk = [&](int j0, int cw, bf16x8* rr, bf16x8* kr, bf16x8* vr) {
    r_load(cw, rr[0], rr[1]);
    r_load(cw + 16, rr[2], rr[3]);
    r_load(cw + 32, rr[4], rr[5]);
    const unsigned short* kp0 = kbase + (size_t)(j0 + col) * 64;
    const unsigned short* kp1 = kbase + (size_t)(j0 + 16 + col) * 64;
    kr[0] = *(const bf16x8*)kp0;
    kr[1] = *(const bf16x8*)(kp0 + 32);
    kr[2] = *(const bf16x8*)kp1;
    kr[3] = *(const bf16x8*)(kp1 + 32);
    int fb = j0 + quad * 8;
#pragma unroll
    for (int ni = 0; ni < 4; ++ni)
      vr[ni] = *(const bf16x8*)(vbase + (size_t)(ni * 16 + col) * 2048 + fb);
  };

  auto compute_chunk = [&](int j0, bf16x8* rr, bf16x8* kr, bf16x8* vr) {
    f32x4 R0 = r_mm(rr[0], rr[1]);
    f32x4 R1 = r_mm(rr[2], rr[3]);
    f32x4 R2 = r_mm(rr[4], rr[5]);
    f32x4 ac0 = {0.f, 0.f, 0.f, 0.f};
    ac0 = MFMA16(quf[0], kr[0], ac0);
    ac0 = MFMA16(quf[1], kr[1], ac0);
    f32x4 ac1 = {0.f, 0.f, 0.f, 0.f};
    ac1 = MFMA16(quf[0], kr[2], ac1);
    ac1 = MFMA16(quf[1], kr[3], ac1);
#pragma unroll
    for (int r = 0; r < 4; ++r) {
      int w = 15 + col - quad * 4 - r;
      int src = quad * 16 + (w & 15);
      float bd0 = __shfl(R0[r], src, 64);
      float bd1 = __shfl(R1[r], src, 64);
      float bd = (w < 16) ? bd0 : bd1;
      float sc = (ac0[r] + bd) * 0.03125f;
      int masked = (j0 + col) > (ri + quad * 4 + r + 1024);
      float p = masked ? 0.f : __expf(sc);
      srow[r] += p;
      pm[r] = fmaxf(pm[r], p);
      Pb[quad * 4 + r][j0 + col] = f2bf(p);
    }
#pragma unroll
    for (int r = 0; r < 4; ++r) {
      int w = 15 + col - quad * 4 - r;
      int src = quad * 16 + (w & 15);
      float bd0 = __shfl(R1[r], src, 64);
      float bd1 = __shfl(R2[r], src, 64);
      float bd = (w < 16) ? bd0 : bd1;
      float sc = (ac1[r] + bd) * 0.03125f;
      int masked = (j0 + 16 + col) > (ri + quad * 4 + r + 1024);
      float p = masked ? 0.f : __expf(sc);
      srow[r] += p;
      pm[r] = fmaxf(pm[r], p);
      Pb[quad * 4 + r][j0 + 16 + col] = f2bf(p);
    }
    asm volatile("s_waitcnt lgkmcnt(0)" ::: "memory");
    bf16x8 pf = *(const bf16x8*)&Pb[col][j0 + quad * 8];
#pragma unroll
    for (int ni = 0; ni < 4; ++ni) o4[ni] = MFMA16(pf, vr[ni], o4[ni]);
  };

  {
    // two named register sets -> static indexing, no scratch (rule #20)
    bf16x8 Ar[6], Ak[4], Av[4], Br[6], Bk[4], Bv[4];
    int j0 = wave << 5;
    int cw = 1008 - ri + j0;
    load_chunk(j0, cw, Ar, Ak, Av);
    int i = 0;
    while (true) {
      if (i + 1 < myN) load_chunk(j0 + 128, cw + 128, Br, Bk, Bv);
      compute_chunk(j0, Ar, Ak, Av);
      ++i; j0 += 128; cw += 128;
      if (i >= myN) break;
      if (i + 1 < myN) load_chunk(j0 + 128, cw + 128, Ar, Ak, Av);
      compute_chunk(j0, Br, Bk, Bv);
      ++i; j0 += 128; cw += 128;
      if (i >= myN) break;
    }
  }

  // stripe row-sums / row-max (reduce across the 16 col lanes of each quad)
#pragma unroll
  for (int r = 0; r < 4; ++r) {
    float v = srow[r], m = pm[r];
    v += __shfl_xor(v, 1, 64);  m = fmaxf(m, __shfl_xor(m, 1, 64));
    v += __shfl_xor(v, 2, 64);  m = fmaxf(m, __shfl_xor(m, 2, 64));
    v += __shfl_xor(v, 4, 64);  m = fmaxf(m, __shfl_xor(m, 4, 64));
    v += __shfl_xor(v, 8, 64);  m = fmaxf(m, __shfl_xor(m, 8, 64));
    srow[r] = v; pm[r] = m;
  }
  if (col == 0) {
#pragma unroll
    for (int r = 0; r < 4; ++r) Sl[wave][quad * 4 + r] = srow[r];
  }
  if (wave >= 2) {
#pragma unroll
    for (int ni = 0; ni < 4; ++ni)
#pragma unroll
      for (int r = 0; r < 4; ++r)
        Ol[wave - 2][(quad * 4 + r) * 64 + ni * 16 + col] = o4[ni][r];
  }
  __syncthreads();
  if (tid < 16) {
    float rv = 1.f / (Sl[0][tid] + Sl[1][tid] + Sl[2][tid] + Sl[3][tid]);
    Rinv[tid] = rv;
  }
  if (wave < 2) {
#pragma unroll
    for (int ni = 0; ni < 4; ++ni)
#pragma unroll
      for (int r = 0; r < 4; ++r) {
        int ix = (quad * 4 + r) * 64 + ni * 16 + col;
        o4[ni][r] += Ol[wave][ix];
        if (wave == 1) Ol[1][ix] = o4[ni][r];
      }
  }
  __syncthreads();
  if (wave == 0) {
#pragma unroll
    for (int ni = 0; ni < 4; ++ni)
#pragma unroll
      for (int r = 0; r < 4; ++r) {
        int ix = (quad * 4 + r) * 64 + ni * 16 + col;
        o4[ni][r] += Ol[1][ix];
        Ol[0][ix] = o4[ni][r];
      }
  }
  __syncthreads();
  {
    int row = tid >> 4, d0 = (tid & 15) << 2;
    float4 ov = *(const float4*)&Ol[0][row * 64 + d0];
    float rv = Rinv[row];
    ushort4 o;
    o.x = f2bf(ov.x * rv); o.y = f2bf(ov.y * rv);
    o.z = f2bf(ov.z * rv); o.w = f2bf(ov.w * rv);
    *(ushort4*)(ao + ((size_t)(b * 1024 + ri + row)) * 1024 + h * 64 + d0) = o;
  }
  // per-(b,h) max of normalized p
  float pmax = 0.f;
#pragma unroll
  for (int r = 0; r < 4; ++r) pmax = fmaxf(pmax, pm[r] * Rinv[quad * 4 + r]);
  pmax = fmaxf(pmax, __shfl_xor(pmax, 16, 64));
  pmax = fmaxf(pmax, __shfl_xor(pmax, 32, 64));
  if (lane == 0) atomicMax((int*)(amax + bh), __float_as_int(pmax));

  // ---- pass 2: normalized attn write (regular coalesced f32x4, mask -> 0) --
  {
    float* abase = attn + ((size_t)bh * 1024 + ri) * 2048;
#pragma unroll 4
    for (int it = 0; it < 32; ++it) {
      int idx = it * 256 + tid;      // 8192 f32x4 units = 16 rows x 512
      int row = idx >> 9;
      int j = (idx & 511) << 2;
      float rv = Rinv[row];
      int lim = ri + row + 1024;
      ushort4 p4 = *(const ushort4*)&Pb[row][j];
      f32x4 o;
      o[0] = (j + 0 <= lim) ? bf2f(p4.x) * rv : 0.f;
      o[1] = (j + 1 <= lim) ? bf2f(p4.y) * rv : 0.f;
      o[2] = (j + 2 <= lim) ? bf2f(p4.z) * rv : 0.f;
      o[3] = (j + 3 <= lim) ? bf2f(p4.w) * rv : 0.f;
      *(f32x4*)(abase + (size_t)row * 2048 + j) = o;
    }
  }
}

// ---------------------------------------------------------------------------
__global__ void k_loss(const float* __restrict__ amax, float* __restrict__ out) {
  int l = threadIdx.x;
  float v = (l < 32) ? amax[l] : 0.f;
  v += __shfl_xor(v, 1, 64);
  v += __shfl_xor(v, 2, 64);
  v += __shfl_xor(v, 4, 64);
  v += __shfl_xor(v, 8, 64);
  v += __shfl_xor(v, 16, 64);
  v += __shfl_xor(v, 32, 64);
  if (l == 0) out[0] = v * (1.f / 32.f);
}

// ---------------------------------------------------------------------------
extern "C" void kernel_launch(void* const* d_in, const int* in_sizes, int n_in,
                              void* d_out, int out_size, void* d_ws, size_t ws_size,
                              hipStream_t stream) {
  (void)in_sizes; (void)n_in; (void)out_size; (void)ws_size;
  const float* inputs = (const float*)d_in[0];
  const float* mem    = (const float*)d_in[1];
  const float* rel    = (const float*)d_in[2];
  const float* ln1g   = (const float*)d_in[4];
  const float* ln1b   = (const float*)d_in[5];
  const float* wq     = (const float*)d_in[6];
  const float* wke    = (const float*)d_in[7];
  const float* wkr    = (const float*)d_in[8];
  const float* wv     = (const float*)d_in[9];
  const float* wf     = (const float*)d_in[10];
  const float* up     = (const float*)d_in[11];
  const float* vp     = (const float*)d_in[12];
  const float* ln2g   = (const float*)d_in[13];
  const float* ln2b   = (const float*)d_in[14];
  const float* w1     = (const float*)d_in[15];
  const float* b1     = (const float*)d_in[16];
  const float* w2     = (const float*)d_in[17];
  const float* b2     = (const float*)d_in[18];
  const float* wg1    = (const float*)d_in[19];
  const float* bg1    = (const float*)d_in[20];
  const float* wg2    = (const float*)d_in[21];
  const float* bg2    = (const float*)d_in[22];

  char* ws = (char*)d_ws;
  unsigned short* wT  = (unsigned short*)(ws);              // 18 MB (9 x 1Mel)
  unsigned short* xt  = (unsigned short*)(ws + 18874368);   // 8 MB
  unsigned short* inb = (unsigned short*)(ws + 27262976);   // 4 MB
  unsigned short* reb = (unsigned short*)(ws + 31457280);   // 4 MB
  unsigned short* kb  = (unsigned short*)(ws + 35651584);   // 8 MB (b,h,f,d)
  unsigned short* vTb = (unsigned short*)(ws + 44040192);   // 8 MB
  unsigned short* qub = (unsigned short*)(ws + 52428800);   // 4 MB
  unsigned short* qvb = (unsigned short*)(ws + 56623104);   // 4 MB
  unsigned short* Qrb = (unsigned short*)(ws + 60817408);   // 4 MB (h,f,d)
  float* amax         = (float*)(ws + 65011712);            // 128 B
  // aliases onto dead buffers:
  unsigned short* vb = qub;          // v row-major, dead after k_tr (8 MB)
  float* rmha = (float*)xt;
  unsigned short* aob = reb;
  float* g1f = (float*)kb;
  float* h2f = (float*)vTb;
  unsigned short* g1b = qub;
  unsigned short* h0b = qvb;
  unsigned short* h1b = Qrb;

  float* outp  = (float*)d_out;
  float* attnp = outp + 2097152;
  float* lossp = outp + 69206016;

  W9 wp;
  wp.p[0] = wq;  wp.p[1] = wke; wp.p[2] = wv;  wp.p[3] = wkr; wp.p[4] = wf;
  wp.p[5] = w1;  wp.p[6] = w2;  wp.p[7] = wg1; wp.p[8] = wg2;

  k_init<<<8448, 256, 0, stream>>>(inputs, mem, rel, ln1g, ln1b, wp,
                                   xt, inb, reb, wT, amax);
  // k|v fused: (B*F,1024) @ [wke|wv]^T  (N=2048); k -> (b,h,f,d), v row-major
  k_gemm<EP_KV, 64><<<dim3(16, 64), 256, 0, stream>>>(
      xt, wT + (1u << 20), 0, 0, nullptr, nullptr, nullptr, kb, vb);
  // vT (b,h,d,f) from v (b,f,h,d)
  k_tr<<<dim3(32, 32), 256, 0, stream>>>(vb, vTb);
  // q -> qu = q+u_param, qv = q+v_param  (A rows = x_tilde[:, -S:]) — clobbers vb
  k_gemm<EP_QUV, 32><<<dim3(8, 64), 256, 0, stream>>>(
      xt, wT, 1024, 1024, nullptr, up, vp, qub, qvb);
  // Qr = rel_enc @ wkr -> (h,f,d)
  k_gemm<EP_QR, 32><<<dim3(8, 64), 256, 0, stream>>>(
      reb, wT + 3u * (1u << 20), 0, 0, nullptr, nullptr, nullptr, Qrb, nullptr);
  // attention: normalized attn directly (in-LDS p tile), ao, amax
  k_att<<<dim3(32, 64), 256, 0, stream>>>(qub, qvb, kb, vTb, Qrb,
                                          attnp, aob, amax);
  // ---- tail (TN=64 occupancy experiment: k_gemm2, 1024 blocks = 4/CU) ----
  // rmha = gelu(ao @ wf)
  k_gemm2<EP_GELU_F32><<<dim3(16, 64), 256, 0, stream>>>(
      aob, wT + 4u * (1u << 20), nullptr, nullptr, nullptr, rmha, nullptr);
  // g1 = inputs + sigmoid(inputs@wg1 + bg1) * rmha
  k_gemm2<EP_GATE1><<<dim3(16, 64), 256, 0, stream>>>(
      inb, wT + 7u * (1u << 20), bg1, inputs, rmha, g1f, g1b);
  // h0 = LN2(g1)
  k_ln<<<2048, 256, 0, stream>>>(g1f, ln2g, ln2b, h0b);
  // h1 = gelu(h0@w1 + b1)
  k_gemm2<EP_GELU_B_BF16><<<dim3(16, 64), 256, 0, stream>>>(
      h0b, wT + 5u * (1u << 20), b1, nullptr, nullptr, h1b, nullptr);
  // h2 = gelu(h1@w2 + b2)
  k_gemm2<EP_GELU_B_F32><<<dim3(16, 64), 256, 0, stream>>>(
      h1b, wT + 6u * (1u << 20), b2, nullptr, nullptr, h2f, nullptr);
  // out = g1 + sigmoid(g1@wg2 + bg2) * h2
  k_gemm2<EP_GATE2><<<dim3(16, 64), 256, 0, stream>>>(
      g1b, wT + 8u * (1u << 20), bg2, g1f, h2f, outp, nullptr);
  k_loss<<<1, 64, 0, stream>>>(amax, lossp);
}

// Round 13
// 638.309 us; speedup vs baseline: 1.2781x; 1.0065x over previous
//
#include <hip/hip_runtime.h>
#include <hip/hip_bf16.h>

// ---------------------------------------------------------------------------
// Transformer-XL block on MI355X.  Shapes: B=2, S=1024, M=1024, F=2048,
// D=1024, H=16, dh=64.  Outputs: out[2M] fp32, attn[2*16*1024*2048] fp32,
// loss[1] fp32.
// ---------------------------------------------------------------------------

typedef __attribute__((ext_vector_type(8))) short bf16x8;
typedef __attribute__((ext_vector_type(4))) float f32x4;

#define MFMA16(a, b, c) __builtin_amdgcn_mfma_f32_16x16x32_bf16((a), (b), (c), 0, 0, 0)

__device__ __forceinline__ unsigned short f2bf(float f) {
  union { __hip_bfloat16 h; unsigned short u; } cv;
  cv.h = __float2bfloat16(f);
  return cv.u;
}

__device__ __forceinline__ float bf2f(unsigned short u) {
  return __uint_as_float((unsigned)u << 16);
}

__device__ __forceinline__ float gelu_f(float x) {
  return 0.5f * x * (1.f + erff(x * 0.70710678118654752f));
}

struct W9 { const float* p[9]; };

// ---------------------------------------------------------------------------
// k_init: [0,4096): LN(concat(mem,inputs))->xt bf16, inputs->inb bf16;
// [4096,6144): rel_enc->reb; [6144,8448): weights -> wT bf16 transposed.
// ---------------------------------------------------------------------------
__global__ __launch_bounds__(256) void k_init(
    const float* __restrict__ inputs, const float* __restrict__ mem,
    const float* __restrict__ rel_enc, const float* __restrict__ g1n,
    const float* __restrict__ b1n, W9 wp,
    unsigned short* __restrict__ xt, unsigned short* __restrict__ inb,
    unsigned short* __restrict__ reb, unsigned short* __restrict__ wT,
    float* __restrict__ amax) {
  int bid = blockIdx.x, tid = threadIdx.x;
  if (bid == 0 && tid < 32) amax[tid] = 0.f;
  if (bid < 4096) {
    __shared__ float red[8];
    int b = bid >> 11, fi = bid & 2047;
    const float* src = (fi < 1024)
        ? (mem + ((size_t)(b * 1024 + fi)) * 1024)
        : (inputs + ((size_t)(b * 1024 + fi - 1024)) * 1024);
    float4 x = ((const float4*)src)[tid];
    float s = x.x + x.y + x.z + x.w;
    float ss = x.x * x.x + x.y * x.y + x.z * x.z + x.w * x.w;
#pragma unroll
    for (int m = 32; m > 0; m >>= 1) {
      s += __shfl_down(s, m, 64);
      ss += __shfl_down(ss, m, 64);
    }
    int w = tid >> 6;
    if ((tid & 63) == 0) { red[w] = s; red[4 + w] = ss; }
    __syncthreads();
    s = red[0] + red[1] + red[2] + red[3];
    ss = red[4] + red[5] + red[6] + red[7];
    float mu = s * (1.f / 1024.f);
    float inv = rsqrtf(ss * (1.f / 1024.f) - mu * mu + 1e-5f);
    float4 g = ((const float4*)g1n)[tid];
    float4 bb = ((const float4*)b1n)[tid];
    ushort4 o;
    o.x = f2bf((x.x - mu) * inv * g.x + bb.x);
    o.y = f2bf((x.y - mu) * inv * g.y + bb.y);
    o.z = f2bf((x.z - mu) * inv * g.z + bb.z);
    o.w = f2bf((x.w - mu) * inv * g.w + bb.w);
    ((ushort4*)(xt + (size_t)bid * 1024))[tid] = o;
    if (fi >= 1024) {
      ushort4 r4;
      r4.x = f2bf(x.x); r4.y = f2bf(x.y); r4.z = f2bf(x.z); r4.w = f2bf(x.w);
      ((ushort4*)(inb + ((size_t)(b * 1024 + fi - 1024)) * 1024))[tid] = r4;
    }
  } else if (bid < 6144) {
    int r = bid - 4096;
    float4 x = ((const float4*)(rel_enc + (size_t)r * 1024))[tid];
    ushort4 o;
    o.x = f2bf(x.x); o.y = f2bf(x.y); o.z = f2bf(x.z); o.w = f2bf(x.w);
    ((ushort4*)(reb + (size_t)r * 1024))[tid] = o;
  } else {
    __shared__ float tl[64][65];
    int idx = bid - 6144;
    int m = idx >> 8;
    int t = idx & 255;
    int k0 = (t >> 4) << 6, n0 = (t & 15) << 6;
    const float* srcw = wp.p[m];
    int kr = tid >> 4, nc = (tid & 15) << 2;
#pragma unroll
    for (int i = 0; i < 4; ++i) {
      int krow = i * 16 + kr;
      float4 v = *(const float4*)(srcw + (size_t)(k0 + krow) * 1024 + n0 + nc);
      tl[nc + 0][krow] = v.x;
      tl[nc + 1][krow] = v.y;
      tl[nc + 2][krow] = v.z;
      tl[nc + 3][krow] = v.w;
    }
    __syncthreads();
    int n = tid >> 2, kc0 = (tid & 3) << 4;
    unsigned short* dst = wT + ((size_t)m << 20) + (size_t)(n0 + n) * 1024 + k0 + kc0;
#pragma unroll
    for (int q = 0; q < 4; ++q) {
      ushort4 o;
      o.x = f2bf(tl[n][kc0 + q * 4 + 0]);
      o.y = f2bf(tl[n][kc0 + q * 4 + 1]);
      o.z = f2bf(tl[n][kc0 + q * 4 + 2]);
      o.w = f2bf(tl[n][kc0 + q * 4 + 3]);
      *(ushort4*)(dst + q * 4) = o;
    }
  }
}

// ---------------------------------------------------------------------------
// k_ln: LayerNorm rows of fp32 (2048 x 1024) -> bf16
// ---------------------------------------------------------------------------
__global__ __launch_bounds__(256) void k_ln(
    const float* __restrict__ xin, const float* __restrict__ g1n,
    const float* __restrict__ b1n, unsigned short* __restrict__ outb) {
  __shared__ float red[8];
  int bid = blockIdx.x, tid = threadIdx.x;
  const float* src = xin + (size_t)bid * 1024;
  float4 x = ((const float4*)src)[tid];
  float s = x.x + x.y + x.z + x.w;
  float ss = x.x * x.x + x.y * x.y + x.z * x.z + x.w * x.w;
#pragma unroll
  for (int m = 32; m > 0; m >>= 1) {
    s += __shfl_down(s, m, 64);
    ss += __shfl_down(ss, m, 64);
  }
  int w = tid >> 6;
  if ((tid & 63) == 0) { red[w] = s; red[4 + w] = ss; }
  __syncthreads();
  s = red[0] + red[1] + red[2] + red[3];
  ss = red[4] + red[5] + red[6] + red[7];
  float mu = s * (1.f / 1024.f);
  float inv = rsqrtf(ss * (1.f / 1024.f) - mu * mu + 1e-5f);
  float4 g = ((const float4*)g1n)[tid];
  float4 bb = ((const float4*)b1n)[tid];
  ushort4 o;
  o.x = f2bf((x.x - mu) * inv * g.x + bb.x);
  o.y = f2bf((x.y - mu) * inv * g.y + bb.y);
  o.z = f2bf((x.z - mu) * inv * g.z + bb.z);
  o.w = f2bf((x.w - mu) * inv * g.w + bb.w);
  ((ushort4*)(outb + (size_t)bid * 1024))[tid] = o;
}

// ---------------------------------------------------------------------------
// GEMM (R9-proven): C[M,Nt] = A[M,1024] @ Wt[Nt,1024]^T, tile TM x 128,
// BK=64, 4 waves split the 128-col dim.  Double-buffered LDS.
// EP_KV writes k in (b,h,f,d); EP_QR writes Qr in (h,f,d).
// KV and QUV stay on this kernel (R12 post-mortem: migrating them to the
// new core NaN'd twice; only the R11-proven tail migration is kept, plus
// the QR-only migration this round isolates).
// ---------------------------------------------------------------------------
__device__ __forceinline__ int lds_u128(int r, int g) {
  return g * 128 + (r & ~7) + ((r ^ g) & 7);
}
template <int TM>
__device__ __forceinline__ int lds_uT(int r, int g) {
  return g * TM + (r & ~7) + ((r ^ g) & 7);
}
__device__ __forceinline__ int lds_u64s(int r, int g) {
  return g * 64 + (r & ~7) + ((r ^ g) & 7);
}

enum { EP_KV = 0, EP_QUV, EP_QR, EP_GELU_F32, EP_GATE1,
       EP_GELU_B_BF16, EP_GELU_B_F32, EP_GATE2 };

template <int EP, int TM>
__global__ __launch_bounds__(256, TM == 32 ? 4 : 3) void k_gemm(
    const unsigned short* __restrict__ A, const unsigned short* __restrict__ Bw,
    int arow_add, int arow_mul,
    const float* __restrict__ bias, const float* __restrict__ auxA,
    const float* __restrict__ auxB, void* __restrict__ out0,
    void* __restrict__ out1) {
  constexpr int MI = TM / 16;
  constexpr int AU = TM / 32;
  __shared__ __align__(16) unsigned short As[2][TM * 64];
  __shared__ __align__(16) unsigned short Bs[2][128 * 64];
  int tid = threadIdx.x;
  int lane = tid & 63, wave = tid >> 6;
  int quad = lane >> 4, col = lane & 15;
  int bm = blockIdx.y, bn = blockIdx.x;
  f32x4 acc[MI][2] = {};
  int str = tid >> 3, stg = tid & 7;
  const unsigned short* aptr[AU];
  int au[AU];
  const unsigned short* bptr[4];
  int bu[4];
#pragma unroll
  for (int i = 0; i < AU; ++i) {
    int r = str + 32 * i;
    int gr = bm * TM + r;
    int ar = gr + arow_add + (gr >> 10) * arow_mul;
    aptr[i] = A + (size_t)ar * 1024 + stg * 8;
    au[i] = lds_uT<TM>(r, stg);
  }
#pragma unroll
  for (int i = 0; i < 4; ++i) {
    int r = str + 32 * i;
    bptr[i] = Bw + (size_t)(bn * 128 + r) * 1024 + stg * 8;
    bu[i] = lds_u128(r, stg);
  }
  uint4 av[AU], bv[4];
#pragma unroll
  for (int i = 0; i < AU; ++i) av[i] = *(const uint4*)(aptr[i]);
#pragma unroll
  for (int i = 0; i < 4; ++i) bv[i] = *(const uint4*)(bptr[i]);
#pragma unroll
  for (int i = 0; i < AU; ++i) ((uint4*)As[0])[au[i]] = av[i];
#pragma unroll
  for (int i = 0; i < 4; ++i) ((uint4*)Bs[0])[bu[i]] = bv[i];
  for (int kt = 0; kt < 16; ++kt) {
    __syncthreads();
    if (kt < 15) {
      int k0 = (kt + 1) * 64;
#pragma unroll
      for (int i = 0; i < AU; ++i) av[i] = *(const uint4*)(aptr[i] + k0);
#pragma unroll
      for (int i = 0; i < 4; ++i) bv[i] = *(const uint4*)(bptr[i] + k0);
    }
    int cur = kt & 1;
#pragma unroll
    for (int ks = 0; ks < 2; ++ks) {
      bf16x8 af[MI], bfr[2];
#pragma unroll
      for (int mi = 0; mi < MI; ++mi)
        af[mi] = ((const bf16x8*)As[cur])[lds_uT<TM>(mi * 16 + col, ks * 4 + quad)];
#pragma unroll
      for (int ni = 0; ni < 2; ++ni)
        bfr[ni] = ((const bf16x8*)Bs[cur])[lds_u128(wave * 32 + ni * 16 + col, ks * 4 + quad)];
#pragma unroll
      for (int mi = 0; mi < MI; ++mi)
#pragma unroll
        for (int ni = 0; ni < 2; ++ni)
          acc[mi][ni] = MFMA16(af[mi], bfr[ni], acc[mi][ni]);
    }
    if (kt < 15) {
      int nxt = cur ^ 1;
#pragma unroll
      for (int i = 0; i < AU; ++i) ((uint4*)As[nxt])[au[i]] = av[i];
#pragma unroll
      for (int i = 0; i < 4; ++i) ((uint4*)Bs[nxt])[bu[i]] = bv[i];
    }
  }
#pragma unroll
  for (int mi = 0; mi < MI; ++mi)
#pragma unroll
    for (int ni = 0; ni < 2; ++ni)
#pragma unroll
      for (int r = 0; r < 4; ++r) {
        int grow = bm * TM + mi * 16 + quad * 4 + r;
        int gcol = bn * 128 + wave * 32 + ni * 16 + col;
        float v = acc[mi][ni][r];
        size_t idx = (size_t)grow * 1024 + gcol;
        if constexpr (EP == EP_KV) {
          if (gcol < 1024) {
            // k -> (b,h,f,d): b=grow>>11, f=grow&2047, h=gcol>>6, d=gcol&63
            size_t ki = (((size_t)(grow >> 11) * 16 + (gcol >> 6)) * 2048 +
                         (grow & 2047)) * 64 + (gcol & 63);
            ((unsigned short*)out0)[ki] = f2bf(v);
          } else {
            ((unsigned short*)out1)[(size_t)grow * 1024 + gcol - 1024] = f2bf(v);
          }
        } else if constexpr (EP == EP_QUV) {
          ((unsigned short*)out0)[idx] = f2bf(v + auxA[gcol]);
          ((unsigned short*)out1)[idx] = f2bf(v + auxB[gcol]);
        } else if constexpr (EP == EP_QR) {
          // Qr -> (h,f,d): f=grow, h=gcol>>6, d=gcol&63
          size_t qi = ((size_t)(gcol >> 6) * 2048 + grow) * 64 + (gcol & 63);
          ((unsigned short*)out0)[qi] = f2bf(v);
        } else if constexpr (EP == EP_GELU_F32) {
          ((float*)out0)[idx] = gelu_f(v);
        } else if constexpr (EP == EP_GATE1) {
          float a = v + bias[gcol];
          float sg = 1.f / (1.f + __expf(-a));
          float g1 = auxA[idx] + sg * auxB[idx];
          ((float*)out0)[idx] = g1;
          ((unsigned short*)out1)[idx] = f2bf(g1);
        } else if constexpr (EP == EP_GELU_B_BF16) {
          ((unsigned short*)out0)[idx] = f2bf(gelu_f(v + bias[gcol]));
        } else if constexpr (EP == EP_GELU_B_F32) {
          ((float*)out0)[idx] = gelu_f(v + bias[gcol]);
        } else {  // EP_GATE2
          float a = v + bias[gcol];
          float sg = 1.f / (1.f + __expf(-a));
          ((float*)out0)[idx] = auxA[idx] + sg * auxB[idx];
        }
      }
}

// ---------------------------------------------------------------------------
// k_gemm2 (R11 bench-proven): TM=32, TN=64, grid (N/64, M/32) -> >=1024
// blocks = 4 blocks/CU (LDS 24 KB).  No min-blocks bound.  Per thread:
// 1 A-store, 2 B-stores (bijective); per wave: 16 output cols, acc[2].
// R13 isolation step: add ONLY the EP_QR branch (verbatim from k_gemm's
// passing epilogue); KV/QUV stay on k_gemm.
// ---------------------------------------------------------------------------
template <int EP>
__global__ __launch_bounds__(256) void k_gemm2(
    const unsigned short* __restrict__ A, const unsigned short* __restrict__ Bw,
    const float* __restrict__ bias, const float* __restrict__ auxA,
    const float* __restrict__ auxB, void* __restrict__ out0,
    void* __restrict__ out1) {
  __shared__ __align__(16) unsigned short As[2][32 * 64];
  __shared__ __align__(16) unsigned short Bs[2][64 * 64];
  int tid = threadIdx.x;
  int lane = tid & 63, wave = tid >> 6;
  int quad = lane >> 4, col = lane & 15;
  int bm = blockIdx.y, bn = blockIdx.x;
  f32x4 acc[2] = {};
  int str = tid >> 3, stg = tid & 7;
  const unsigned short* aptr = A + (size_t)(bm * 32 + str) * 1024 + stg * 8;
  int au = lds_uT<32>(str, stg);
  const unsigned short* bptr0 = Bw + (size_t)(bn * 64 + str) * 1024 + stg * 8;
  const unsigned short* bptr1 = bptr0 + (size_t)32 * 1024;
  int bu0 = lds_u64s(str, stg);
  int bu1 = lds_u64s(str + 32, stg);
  uint4 av = *(const uint4*)aptr;
  uint4 bv0 = *(const uint4*)bptr0;
  uint4 bv1 = *(const uint4*)bptr1;
  ((uint4*)As[0])[au] = av;
  ((uint4*)Bs[0])[bu0] = bv0;
  ((uint4*)Bs[0])[bu1] = bv1;
  for (int kt = 0; kt < 16; ++kt) {
    __syncthreads();
    if (kt < 15) {
      int k0 = (kt + 1) * 64;
      av = *(const uint4*)(aptr + k0);
      bv0 = *(const uint4*)(bptr0 + k0);
      bv1 = *(const uint4*)(bptr1 + k0);
    }
    int cur = kt & 1;
#pragma unroll
    for (int ks = 0; ks < 2; ++ks) {
      bf16x8 af0 = ((const bf16x8*)As[cur])[lds_uT<32>(col, ks * 4 + quad)];
      bf16x8 af1 = ((const bf16x8*)As[cur])[lds_uT<32>(16 + col, ks * 4 + quad)];
      bf16x8 bf0 = ((const bf16x8*)Bs[cur])[lds_u64s(wave * 16 + col, ks * 4 + quad)];
      acc[0] = MFMA16(af0, bf0, acc[0]);
      acc[1] = MFMA16(af1, bf0, acc[1]);
    }
    if (kt < 15) {
      int nxt = cur ^ 1;
      ((uint4*)As[nxt])[au] = av;
      ((uint4*)Bs[nxt])[bu0] = bv0;
      ((uint4*)Bs[nxt])[bu1] = bv1;
    }
  }
#pragma unroll
  for (int mi = 0; mi < 2; ++mi)
#pragma unroll
    for (int r = 0; r < 4; ++r) {
      int grow = bm * 32 + mi * 16 + quad * 4 + r;
      int gcol = bn * 64 + wave * 16 + col;
      float v = acc[mi][r];
      size_t idx = (size_t)grow * 1024 + gcol;
      if constexpr (EP == EP_QR) {
        // Qr -> (h,f,d): f=grow, h=gcol>>6, d=gcol&63
        size_t qi = ((size_t)(gcol >> 6) * 2048 + grow) * 64 + (gcol & 63);
        ((unsigned short*)out0)[qi] = f2bf(v);
      } else if constexpr (EP == EP_GELU_F32) {
        ((float*)out0)[idx] = gelu_f(v);
      } else if constexpr (EP == EP_GATE1) {
        float a = v + bias[gcol];
        float sg = 1.f / (1.f + __expf(-a));
        float g1 = auxA[idx] + sg * auxB[idx];
        ((float*)out0)[idx] = g1;
        ((unsigned short*)out1)[idx] = f2bf(g1);
      } else if constexpr (EP == EP_GELU_B_BF16) {
        ((unsigned short*)out0)[idx] = f2bf(gelu_f(v + bias[gcol]));
      } else if constexpr (EP == EP_GELU_B_F32) {
        ((float*)out0)[idx] = gelu_f(v + bias[gcol]);
      } else {  // EP_GATE2
        float a = v + bias[gcol];
        float sg = 1.f / (1.f + __expf(-a));
        ((float*)out0)[idx] = auxA[idx] + sg * auxB[idx];
      }
    }
}

// ---------------------------------------------------------------------------
// k_tr: v (b,f,h,d) bf16 -> vT (b,h,d,f) bf16.  grid (32 bh, 32 ftile).
// ---------------------------------------------------------------------------
__global__ __launch_bounds__(256) void k_tr(
    const unsigned short* __restrict__ v, unsigned short* __restrict__ vT) {
  __shared__ unsigned short tl[64][72];
  int bh = blockIdx.x, ft = blockIdx.y;
  int b = bh >> 4, h = bh & 15;
  int f0 = ft * 64;
  int tid = threadIdx.x;
  int fr = tid >> 2, c0 = (tid & 3) * 16;
  *(uint4*)&tl[fr][c0] =
      *(const uint4*)(v + ((size_t)(b * 2048 + f0 + fr)) * 1024 + h * 64 + c0);
  __syncthreads();
  int dr = tid >> 2, fc = (tid & 3) * 16;
  unsigned short* dst =
      vT + (((size_t)(b * 16 + h) * 64 + dr)) * 2048 + f0 + fc;
#pragma unroll
  for (int q = 0; q < 4; ++q) {
    ushort4 o;
    o.x = tl[fc + q * 4 + 0][dr];
    o.y = tl[fc + q * 4 + 1][dr];
    o.z = tl[fc + q * 4 + 2][dr];
    o.w = tl[fc + q * 4 + 3][dr];
    *(ushort4*)(dst + q * 4) = o;
  }
}

// ---------------------------------------------------------------------------
// Fused rel-pos attention (R9-benched version, unchanged).
// grid (32 = B*H, 64 = S/16); block 256 = 4 waves, 2 blocks/CU.
// k in (b,h,f,d), Qr in (h,f,d) (contiguous rows); V in (b,h,d,f).
// Pass 1: p (bf16) into LDS tile Pb[16][2048+pad], rowsum + P@V in regs.
// Cross-wave reduce -> Rinv, O.  ao (bf16) + amax.
// Pass 2: stream Pb * rinv -> attn (fp32), regular coalesced f32x4 stores.
// ---------------------------------------------------------------------------
__global__ __launch_bounds__(256) void k_att(
    const unsigned short* __restrict__ qu, const unsigned short* __restrict__ qv,
    const unsigned short* __restrict__ kk, const unsigned short* __restrict__ vT,
    const unsigned short* __restrict__ Qr,
    float* __restrict__ attn, unsigned short* __restrict__ ao,
    float* __restrict__ amax) {
  __shared__ __align__(16) unsigned short Pb[16][2056];
  __shared__ __align__(16) float Ol[2][1024];
  __shared__ float Sl[4][16];
  __shared__ float Rinv[16];
  int tid = threadIdx.x, lane = tid & 63, wave = tid >> 6;
  int quad = lane >> 4, col = lane & 15;
  int bh = blockIdx.x, rt = blockIdx.y;
  int b = bh >> 4, h = bh & 15;
  int ri = rt * 16;

  bf16x8 quf[2], qvf[2];
  {
    const unsigned short* p0 = qu + ((size_t)(b * 1024 + ri + col)) * 1024 + h * 64 + quad * 8;
    quf[0] = *(const bf16x8*)p0;
    quf[1] = *(const bf16x8*)(p0 + 32);
    const unsigned short* p1 = qv + ((size_t)(b * 1024 + ri + col)) * 1024 + h * 64 + quad * 8;
    qvf[0] = *(const bf16x8*)p1;
    qvf[1] = *(const bf16x8*)(p1 + 32);
  }

  // Qr in (h,f,d): rows contiguous (64 bf16 apart)
  const unsigned short* qrbase = Qr + (size_t)h * 2048 * 64 + quad * 8;
  auto r_load = [&](int cbase, bf16x8& b0, bf16x8& b1) {
    int cr = cbase + col;
    cr = cr < 0 ? 0 : (cr > 2047 ? 2047 : cr);
    const unsigned short* p = qrbase + (size_t)cr * 64;
    b0 = *(const bf16x8*)p;
    b1 = *(const bf16x8*)(p + 32);
  };
  auto r_mm = [&](bf16x8 b0, bf16x8 b1) -> f32x4 {
    f32x4 z = {0.f, 0.f, 0.f, 0.f};
    z = MFMA16(qvf[0], b0, z);
    z = MFMA16(qvf[1], b1, z);
    return z;
  };

  // k in (b,h,f,d): rows contiguous (64 bf16 apart)
  const unsigned short* kbase = kk + ((size_t)(b * 16 + h)) * 2048 * 64 + quad * 8;
  const unsigned short* vbase = vT + ((size_t)((b * 16 + h) * 64)) * 2048;

  f32x4 o4[4] = {};
  f32x4 srow = {0.f, 0.f, 0.f, 0.f};
  f32x4 pm = {0.f, 0.f, 0.f, 0.f};
  int jmax = ri + 15 + 1024;
  int NA = (jmax >> 5) + 1;                 // active 32-col chunks (33..64)
  int myN = (NA - wave + 3) >> 2;           // chunks owned by this wave (>=8)

  // --- per-chunk loads: 6 rel (3 tiles) + 4 K + 4 V bf16x8 regs ---
  auto load_chunk = [&](int j0, int cw, bf16x8* rr, bf16x8* kr, bf16x8* vr) {
    r_load(cw, rr[0], rr[1]);
    r_load(cw + 16, rr[2], rr[3]);
    r_load(cw + 32, rr[4], rr[5]);
    const unsigned short* kp0 = kbase + (size_t)(j0 + col) * 64;
    const unsigned short* kp1 = kbase + (size_t)(j0 + 16 + col) * 64;
    kr[0] = *(const bf16x8*)kp0;
    kr[1] = *(const bf16x8*)(kp0 + 32);
    kr[2] = *(const bf16x8*)kp1;
    kr[3] = *(const bf16x8*)(kp1 + 32);
    int fb = j0 + quad * 8;
#pragma unroll
    for (int ni = 0; ni < 4; ++ni)
      vr[ni] = *(const bf16x8*)(vbase + (size_t)(ni * 16 + col) * 2048 + fb);
  };

  auto compute_chunk = [&](int j0, bf16x8* rr, bf16x8* kr, bf16x8* vr) {
    f32x4 R0 = r_mm(rr[0], rr[1]);
    f32x4 R1 = r_mm(rr[2], rr[3]);
    f32x4 R2 = r_mm(rr[4], rr[5]);
    f32x4 ac0 = {0.f, 0.f, 0.f, 0.f};
    ac0 = MFMA16(quf[0], kr[0], ac0);
    ac0 = MFMA16(quf[1], kr[1], ac0);
    f32x4 ac1 = {0.f, 0.f, 0.f, 0.f};
    ac1 = MFMA16(quf[0], kr[2], ac1);
    ac1 = MFMA16(quf[1], kr[3], ac1);
#pragma unroll
    for (int r = 0; r < 4; ++r) {
      int w = 15 + col - quad * 4 - r;
      int src = quad * 16 + (w & 15);
      float bd0 = __shfl(R0[r], src, 64);
      float bd1 = __shfl(R1[r], src, 64);
      float bd = (w < 16) ? bd0 : bd1;
      float sc = (ac0[r] + bd) * 0.03125f;
      int masked = (j0 + col) > (ri + quad * 4 + r + 1024);
      float p = masked ? 0.f : __expf(sc);
      srow[r] += p;
      pm[r] = fmaxf(pm[r], p);
      Pb[quad * 4 + r][j0 + col] = f2bf(p);
    }
#pragma unroll
    for (int r = 0; r < 4; ++r) {
      int w = 15 + col - quad * 4 - r;
      int src = quad * 16 + (w & 15);
      float bd0 = __shfl(R1[r], src, 64);
      float bd1 = __shfl(R2[r], src, 64);
      float bd = (w < 16) ? bd0 : bd1;
      float sc = (ac1[r] + bd) * 0.03125f;
      int masked = (j0 + 16 + col) > (ri + quad * 4 + r + 1024);
      float p = masked ? 0.f : __expf(sc);
      srow[r] += p;
      pm[r] = fmaxf(pm[r], p);
      Pb[quad * 4 + r][j0 + 16 + col] = f2bf(p);
    }
    asm volatile("s_waitcnt lgkmcnt(0)" ::: "memory");
    bf16x8 pf = *(const bf16x8*)&Pb[col][j0 + quad * 8];
#pragma unroll
    for (int ni = 0; ni < 4; ++ni) o4[ni] = MFMA16(pf, vr[ni], o4[ni]);
  };

  {
    // two named register sets -> static indexing, no scratch (rule #20)
    bf16x8 Ar[6], Ak[4], Av[4], Br[6], Bk[4], Bv[4];
    int j0 = wave << 5;
    int cw = 1008 - ri + j0;
    load_chunk(j0, cw, Ar, Ak, Av);
    int i = 0;
    while (true) {
      if (i + 1 < myN) load_chunk(j0 + 128, cw + 128, Br, Bk, Bv);
      compute_chunk(j0, Ar, Ak, Av);
      ++i; j0 += 128; cw += 128;
      if (i >= myN) break;
      if (i + 1 < myN) load_chunk(j0 + 128, cw + 128, Ar, Ak, Av);
      compute_chunk(j0, Br, Bk, Bv);
      ++i; j0 += 128; cw += 128;
      if (i >= myN) break;
    }
  }

  // stripe row-sums / row-max (reduce across the 16 col lanes of each quad)
#pragma unroll
  for (int r = 0; r < 4; ++r) {
    float v = srow[r], m = pm[r];
    v += __shfl_xor(v, 1, 64);  m = fmaxf(m, __shfl_xor(m, 1, 64));
    v += __shfl_xor(v, 2, 64);  m = fmaxf(m, __shfl_xor(m, 2, 64));
    v += __shfl_xor(v, 4, 64);  m = fmaxf(m, __shfl_xor(m, 4, 64));
    v += __shfl_xor(v, 8, 64);  m = fmaxf(m, __shfl_xor(m, 8, 64));
    srow[r] = v; pm[r] = m;
  }
  if (col == 0) {
#pragma unroll
    for (int r = 0; r < 4; ++r) Sl[wave][quad * 4 + r] = srow[r];
  }
  if (wave >= 2) {
#pragma unroll
    for (int ni = 0; ni < 4; ++ni)
#pragma unroll
      for (int r = 0; r < 4; ++r)
        Ol[wave - 2][(quad * 4 + r) * 64 + ni * 16 + col] = o4[ni][r];
  }
  __syncthreads();
  if (tid < 16) {
    float rv = 1.f / (Sl[0][tid] + Sl[1][tid] + Sl[2][tid] + Sl[3][tid]);
    Rinv[tid] = rv;
  }
  if (wave < 2) {
#pragma unroll
    for (int ni = 0; ni < 4; ++ni)
#pragma unroll
      for (int r = 0; r < 4; ++r) {
        int ix = (quad * 4 + r) * 64 + ni * 16 + col;
        o4[ni][r] += Ol[wave][ix];
        if (wave == 1) Ol[1][ix] = o4[ni][r];
      }
  }
  __syncthreads();
  if (wave == 0) {
#pragma unroll
    for (int ni = 0; ni < 4; ++ni)
#pragma unroll
      for (int r = 0; r < 4; ++r) {
        int ix = (quad * 4 + r) * 64 + ni * 16 + col;
        o4[ni][r] += Ol[1][ix];
        Ol[0][ix] = o4[ni][r];
      }
  }
  __syncthreads();
  {
    int row = tid >> 4, d0 = (tid & 15) << 2;
    float4 ov = *(const float4*)&Ol[0][row * 64 + d0];
    float rv = Rinv[row];
    ushort4 o;
    o.x = f2bf(ov.x * rv); o.y = f2bf(ov.y * rv);
    o.z = f2bf(ov.z * rv); o.w = f2bf(ov.w * rv);
    *(ushort4*)(ao + ((size_t)(b * 1024 + ri + row)) * 1024 + h * 64 + d0) = o;
  }
  // per-(b,h) max of normalized p
  float pmax = 0.f;
#pragma unroll
  for (int r = 0; r < 4; ++r) pmax = fmaxf(pmax, pm[r] * Rinv[quad * 4 + r]);
  pmax = fmaxf(pmax, __shfl_xor(pmax, 16, 64));
  pmax = fmaxf(pmax, __shfl_xor(pmax, 32, 64));
  if (lane == 0) atomicMax((int*)(amax + bh), __float_as_int(pmax));

  // ---- pass 2: normalized attn write (regular coalesced f32x4, mask -> 0) --
  {
    float* abase = attn + ((size_t)bh * 1024 + ri) * 2048;
#pragma unroll 4
    for (int it = 0; it < 32; ++it) {
      int idx = it * 256 + tid;      // 8192 f32x4 units = 16 rows x 512
      int row = idx >> 9;
      int j = (idx & 511) << 2;
      float rv = Rinv[row];
      int lim = ri + row + 1024;
      ushort4 p4 = *(const ushort4*)&Pb[row][j];
      f32x4 o;
      o[0] = (j + 0 <= lim) ? bf2f(p4.x) * rv : 0.f;
      o[1] = (j + 1 <= lim) ? bf2f(p4.y) * rv : 0.f;
      o[2] = (j + 2 <= lim) ? bf2f(p4.z) * rv : 0.f;
      o[3] = (j + 3 <= lim) ? bf2f(p4.w) * rv : 0.f;
      *(f32x4*)(abase + (size_t)row * 2048 + j) = o;
    }
  }
}

// ---------------------------------------------------------------------------
__global__ void k_loss(const float* __restrict__ amax, float* __restrict__ out) {
  int l = threadIdx.x;
  float v = (l < 32) ? amax[l] : 0.f;
  v += __shfl_xor(v, 1, 64);
  v += __shfl_xor(v, 2, 64);
  v += __shfl_xor(v, 4, 64);
  v += __shfl_xor(v, 8, 64);
  v += __shfl_xor(v, 16, 64);
  v += __shfl_xor(v, 32, 64);
  if (l == 0) out[0] = v * (1.f / 32.f);
}

// ---------------------------------------------------------------------------
extern "C" void kernel_launch(void* const* d_in, const int* in_sizes, int n_in,
                              void* d_out, int out_size, void* d_ws, size_t ws_size,
                              hipStream_t stream) {
  (void)in_sizes; (void)n_in; (void)out_size; (void)ws_size;
  const float* inputs = (const float*)d_in[0];
  const float* mem    = (const float*)d_in[1];
  const float* rel    = (const float*)d_in[2];
  const float* ln1g   = (const float*)d_in[4];
  const float* ln1b   = (const float*)d_in[5];
  const float* wq     = (const float*)d_in[6];
  const float* wke    = (const float*)d_in[7];
  const float* wkr    = (const float*)d_in[8];
  const float* wv     = (const float*)d_in[9];
  const float* wf     = (const float*)d_in[10];
  const float* up     = (const float*)d_in[11];
  const float* vp     = (const float*)d_in[12];
  const float* ln2g   = (const float*)d_in[13];
  const float* ln2b   = (const float*)d_in[14];
  const float* w1     = (const float*)d_in[15];
  const float* b1     = (const float*)d_in[16];
  const float* w2     = (const float*)d_in[17];
  const float* b2     = (const float*)d_in[18];
  const float* wg1    = (const float*)d_in[19];
  const float* bg1    = (const float*)d_in[20];
  const float* wg2    = (const float*)d_in[21];
  const float* bg2    = (const float*)d_in[22];

  char* ws = (char*)d_ws;
  unsigned short* wT  = (unsigned short*)(ws);              // 18 MB (9 x 1Mel)
  unsigned short* xt  = (unsigned short*)(ws + 18874368);   // 8 MB
  unsigned short* inb = (unsigned short*)(ws + 27262976);   // 4 MB
  unsigned short* reb = (unsigned short*)(ws + 31457280);   // 4 MB
  unsigned short* kb  = (unsigned short*)(ws + 35651584);   // 8 MB (b,h,f,d)
  unsigned short* vTb = (unsigned short*)(ws + 44040192);   // 8 MB
  unsigned short* qub = (unsigned short*)(ws + 52428800);   // 4 MB
  unsigned short* qvb = (unsigned short*)(ws + 56623104);   // 4 MB
  unsigned short* Qrb = (unsigned short*)(ws + 60817408);   // 4 MB (h,f,d)
  float* amax         = (float*)(ws + 65011712);            // 128 B
  // aliases onto dead buffers:
  unsigned short* vb = qub;          // v row-major, dead after k_tr (8 MB)
  float* rmha = (float*)xt;
  unsigned short* aob = reb;
  float* g1f = (float*)kb;
  float* h2f = (float*)vTb;
  unsigned short* g1b = qub;
  unsigned short* h0b = qvb;
  unsigned short* h1b = Qrb;

  float* outp  = (float*)d_out;
  float* attnp = outp + 2097152;
  float* lossp = outp + 69206016;

  W9 wp;
  wp.p[0] = wq;  wp.p[1] = wke; wp.p[2] = wv;  wp.p[3] = wkr; wp.p[4] = wf;
  wp.p[5] = w1;  wp.p[6] = w2;  wp.p[7] = wg1; wp.p[8] = wg2;

  k_init<<<8448, 256, 0, stream>>>(inputs, mem, rel, ln1g, ln1b, wp,
                                   xt, inb, reb, wT, amax);
  // k|v fused: (B*F,1024) @ [wke|wv]^T  (N=2048); k -> (b,h,f,d), v row-major
  k_gemm<EP_KV, 64><<<dim3(16, 64), 256, 0, stream>>>(
      xt, wT + (1u << 20), 0, 0, nullptr, nullptr, nullptr, kb, vb);
  // vT (b,h,d,f) from v (b,f,h,d)
  k_tr<<<dim3(32, 32), 256, 0, stream>>>(vb, vTb);
  // q -> qu = q+u_param, qv = q+v_param  (A rows = x_tilde[:, -S:]) — clobbers vb
  k_gemm<EP_QUV, 32><<<dim3(8, 64), 256, 0, stream>>>(
      xt, wT, 1024, 1024, nullptr, up, vp, qub, qvb);
  // Qr = rel_enc @ wkr -> (h,f,d)   [R13: migrated to k_gemm2, isolated]
  k_gemm2<EP_QR><<<dim3(16, 64), 256, 0, stream>>>(
      reb, wT + 3u * (1u << 20), nullptr, nullptr, nullptr, Qrb, nullptr);
  // attention: normalized attn directly (in-LDS p tile), ao, amax
  k_att<<<dim3(32, 64), 256, 0, stream>>>(qub, qvb, kb, vTb, Qrb,
                                          attnp, aob, amax);
  // rmha = gelu(ao @ wf)
  k_gemm2<EP_GELU_F32><<<dim3(16, 64), 256, 0, stream>>>(
      aob, wT + 4u * (1u << 20), nullptr, nullptr, nullptr, rmha, nullptr);
  // g1 = inputs + sigmoid(inputs@wg1 + bg1) * rmha
  k_gemm2<EP_GATE1><<<dim3(16, 64), 256, 0, stream>>>(
      inb, wT + 7u * (1u << 20), bg1, inputs, rmha, g1f, g1b);
  // h0 = LN2(g1)
  k_ln<<<2048, 256, 0, stream>>>(g1f, ln2g, ln2b, h0b);
  // h1 = gelu(h0@w1 + b1)
  k_gemm2<EP_GELU_B_BF16><<<dim3(16, 64), 256, 0, stream>>>(
      h0b, wT + 5u * (1u << 20), b1, nullptr, nullptr, h1b, nullptr);
  // h2 = gelu(h1@w2 + b2)
  k_gemm2<EP_GELU_B_F32><<<dim3(16, 64), 256, 0, stream>>>(
      h1b, wT + 6u * (1u << 20), b2, nullptr, nullptr, h2f, nullptr);
  // out = g1 + sigmoid(g1@wg2 + bg2) * h2
  k_gemm2<EP_GATE2><<<dim3(16, 64), 256, 0, stream>>>(
      g1b, wT + 8u * (1u << 20), bg2, g1f, h2f, outp, nullptr);
  k_loss<<<1, 64, 0, stream>>>(amax, lossp);
}